// Round 1
// baseline (834.297 us; speedup 1.0000x reference)
//
#include <hip/hip_runtime.h>
#include <hip/hip_bf16.h>

#define N_NODES 10000
#define HID 256
#define IN_F 128
#define E_CON 320000
#define E_DST 100000
#define E_TRN 50000

// ---------------- CSR build ----------------

__global__ void hist_kernel(const int* __restrict__ dst, int nE, int* __restrict__ deg) {
    int i = blockIdx.x * blockDim.x + threadIdx.x;
    if (i < nE) atomicAdd(&deg[dst[i]], 1);
}

// Single-block exclusive scan over n elements.
// in/out `cur` (reads deg from cur, writes cursor=excl), writes off[0..n] (off[n]=total).
__global__ void scan_kernel(int* __restrict__ cur, int* __restrict__ off, int n) {
    __shared__ int smem[1024];
    __shared__ int running;
    if (threadIdx.x == 0) running = 0;
    __syncthreads();
    for (int base = 0; base < n; base += 1024) {
        int i = base + threadIdx.x;
        int v = (i < n) ? cur[i] : 0;
        smem[threadIdx.x] = v;
        __syncthreads();
        #pragma unroll
        for (int s = 1; s < 1024; s <<= 1) {
            int t = (threadIdx.x >= s) ? smem[threadIdx.x - s] : 0;
            __syncthreads();
            smem[threadIdx.x] += t;
            __syncthreads();
        }
        int incl = smem[threadIdx.x];
        int excl = incl - v + running;
        if (i < n) { off[i] = excl; cur[i] = excl; }
        __syncthreads();
        if (threadIdx.x == 1023) running += smem[1023];
        __syncthreads();
    }
    if (threadIdx.x == 0) off[n] = running;
}

__global__ void fill_kernel(const int* __restrict__ src, const int* __restrict__ dst,
                            int nE, int* __restrict__ cur, int* __restrict__ srt) {
    int i = blockIdx.x * blockDim.x + threadIdx.x;
    if (i < nE) {
        int p = atomicAdd(&cur[dst[i]], 1);
        srt[p] = src[i];
    }
}

// ---------------- aggregation (segment sum / mean via CSR) ----------------

template <int F, bool MEAN>
__global__ void aggregate_kernel(const float* __restrict__ x, const int* __restrict__ off,
                                 const int* __restrict__ srt, float* __restrict__ msg) {
    int node = blockIdx.x;
    int t = threadIdx.x;   // blockDim.x == F
    int s0 = off[node], s1 = off[node + 1];
    float acc = 0.f;
    for (int e = s0; e < s1; ++e) {
        int s = srt[e];
        acc += x[(size_t)s * F + t];
    }
    if (MEAN) {
        int d = s1 - s0;
        acc *= 1.0f / (float)(d > 1 ? d : 1);
    }
    msg[(size_t)node * F + t] = acc;
}

// ---------------- fused dual GEMM: out = A1@W1 (+ A2@W2) + b, optional relu ----------------
// A: [M,K] row-major, W: [K,256] row-major, out: [M,256]. Tile 64x64, 256 threads, 4x4/thread.

template <bool DUAL, bool RELU>
__global__ __launch_bounds__(256) void gemm_dual(const float* __restrict__ A1,
                                                 const float* __restrict__ W1,
                                                 const float* __restrict__ A2,
                                                 const float* __restrict__ W2,
                                                 const float* __restrict__ bias,
                                                 float* __restrict__ out, int M, int K) {
    __shared__ float As[64][20];   // row stride 80B -> float4-aligned
    __shared__ float Ws[16][68];   // row stride 272B -> float4-aligned
    int tid = threadIdx.x;
    int tx = tid & 15, ty = tid >> 4;
    int row0 = blockIdx.x * 64;
    int col0 = blockIdx.y * 64;

    int larow = tid >> 2;          // 0..63
    int lak   = (tid & 3) * 4;     // 0,4,8,12
    int lwrow = tid >> 4;          // 0..15
    int lwcol = (tid & 15) * 4;    // 0..60

    float acc[4][4] = {};

    int npass = DUAL ? 2 : 1;
    for (int pass = 0; pass < npass; ++pass) {
        const float* __restrict__ A = pass ? A2 : A1;
        const float* __restrict__ W = pass ? W2 : W1;
        for (int k0 = 0; k0 < K; k0 += 16) {
            int ar = row0 + larow;
            float4 av = make_float4(0.f, 0.f, 0.f, 0.f);
            if (ar < M) av = *(const float4*)&A[(size_t)ar * K + k0 + lak];
            *(float4*)&As[larow][lak] = av;
            float4 wv = *(const float4*)&W[(size_t)(k0 + lwrow) * HID + col0 + lwcol];
            *(float4*)&Ws[lwrow][lwcol] = wv;
            __syncthreads();
            #pragma unroll
            for (int kk = 0; kk < 16; ++kk) {
                float a[4], w[4];
                #pragma unroll
                for (int i = 0; i < 4; ++i) a[i] = As[ty * 4 + i][kk];
                #pragma unroll
                for (int j = 0; j < 4; ++j) w[j] = Ws[kk][tx * 4 + j];
                #pragma unroll
                for (int i = 0; i < 4; ++i)
                    #pragma unroll
                    for (int j = 0; j < 4; ++j)
                        acc[i][j] += a[i] * w[j];
            }
            __syncthreads();
        }
    }

    int c = col0 + tx * 4;
    float b0 = bias[c + 0], b1 = bias[c + 1], b2 = bias[c + 2], b3 = bias[c + 3];
    #pragma unroll
    for (int i = 0; i < 4; ++i) {
        int r = row0 + ty * 4 + i;
        if (r < M) {
            float4 o;
            o.x = acc[i][0] + b0;
            o.y = acc[i][1] + b1;
            o.z = acc[i][2] + b2;
            o.w = acc[i][3] + b3;
            if (RELU) {
                o.x = fmaxf(o.x, 0.f); o.y = fmaxf(o.y, 0.f);
                o.z = fmaxf(o.z, 0.f); o.w = fmaxf(o.w, 0.f);
            }
            *(float4*)&out[(size_t)r * HID + c] = o;
        }
    }
}

// ---------------- launch ----------------

static inline char* align256(char* p) {
    return (char*)(((uintptr_t)p + 255) & ~(uintptr_t)255);
}

extern "C" void kernel_launch(void* const* d_in, const int* in_sizes, int n_in,
                              void* d_out, int out_size, void* d_ws, size_t ws_size,
                              hipStream_t stream) {
    const float* x0     = (const float*)d_in[0];
    const int*   ei_con = (const int*)d_in[1];
    const int*   ei_dst = (const int*)d_in[2];
    const int*   ei_trn = (const int*)d_in[3];
    const float* Wroot1 = (const float*)d_in[4];
    const float* Wrel1  = (const float*)d_in[5];
    const float* b1     = (const float*)d_in[6];
    const float* Wroot2 = (const float*)d_in[7];
    const float* Wrel2  = (const float*)d_in[8];
    const float* b2     = (const float*)d_in[9];
    const float* Wroot3 = (const float*)d_in[10];
    const float* Wrel3  = (const float*)d_in[11];
    const float* b3     = (const float*)d_in[12];
    const float* Wroot4 = (const float*)d_in[13];
    const float* Wrel4  = (const float*)d_in[14];
    const float* b4     = (const float*)d_in[15];
    const float* Wroot5 = (const float*)d_in[16];
    const float* Wrel5  = (const float*)d_in[17];
    const float* b5     = (const float*)d_in[18];
    const float* WL     = (const float*)d_in[19];
    const float* bL     = (const float*)d_in[20];

    const int eCon = in_sizes[1] / 2;
    const int eDst = in_sizes[2] / 2;
    const int eTrn = in_sizes[3] / 2;
    const int* src_con = ei_con;           const int* dst_con = ei_con + eCon;
    const int* src_dst = ei_dst;           const int* dst_dst = ei_dst + eDst;
    const int* src_trn = ei_trn;           const int* dst_trn = ei_trn + eTrn;

    char* p = (char*)d_ws;
    int* off_con = (int*)p; p = align256(p + (N_NODES + 1) * 4);
    int* cur_con = (int*)p; p = align256(p + N_NODES * 4);
    int* off_dst = (int*)p; p = align256(p + (N_NODES + 1) * 4);
    int* cur_dst = (int*)p; p = align256(p + N_NODES * 4);
    int* off_trn = (int*)p; p = align256(p + (N_NODES + 1) * 4);
    int* cur_trn = (int*)p; p = align256(p + N_NODES * 4);
    int* srt_con = (int*)p; p = align256(p + E_CON * 4);
    int* srt_dst = (int*)p; p = align256(p + E_DST * 4);
    int* srt_trn = (int*)p; p = align256(p + E_TRN * 4);
    float* msg = (float*)p; p = align256(p + (size_t)N_NODES * HID * 4);
    float* xa  = (float*)p; p = align256(p + (size_t)N_NODES * HID * 4);
    float* xb  = (float*)p; p = align256(p + (size_t)N_NODES * HID * 4);
    float* outp = (float*)d_out;

    // ---- CSR build for all 3 graphs ----
    hipMemsetAsync(cur_con, 0, N_NODES * 4, stream);
    hipMemsetAsync(cur_dst, 0, N_NODES * 4, stream);
    hipMemsetAsync(cur_trn, 0, N_NODES * 4, stream);
    hist_kernel<<<(eCon + 255) / 256, 256, 0, stream>>>(dst_con, eCon, cur_con);
    hist_kernel<<<(eDst + 255) / 256, 256, 0, stream>>>(dst_dst, eDst, cur_dst);
    hist_kernel<<<(eTrn + 255) / 256, 256, 0, stream>>>(dst_trn, eTrn, cur_trn);
    scan_kernel<<<1, 1024, 0, stream>>>(cur_con, off_con, N_NODES);
    scan_kernel<<<1, 1024, 0, stream>>>(cur_dst, off_dst, N_NODES);
    scan_kernel<<<1, 1024, 0, stream>>>(cur_trn, off_trn, N_NODES);
    fill_kernel<<<(eCon + 255) / 256, 256, 0, stream>>>(src_con, dst_con, eCon, cur_con, srt_con);
    fill_kernel<<<(eDst + 255) / 256, 256, 0, stream>>>(src_dst, dst_dst, eDst, cur_dst, srt_dst);
    fill_kernel<<<(eTrn + 255) / 256, 256, 0, stream>>>(src_trn, dst_trn, eTrn, cur_trn, srt_trn);

    dim3 ggrid((N_NODES + 63) / 64, HID / 64);

    // conv1: x -> xa (relu, add, connections, K=128)
    aggregate_kernel<IN_F, false><<<N_NODES, IN_F, 0, stream>>>(x0, off_con, srt_con, msg);
    gemm_dual<true, true><<<ggrid, 256, 0, stream>>>(msg, Wrel1, x0, Wroot1, b1, xa, N_NODES, IN_F);

    // conv2: xa -> xb (no relu, add, trains, K=256)
    aggregate_kernel<HID, false><<<N_NODES, HID, 0, stream>>>(xa, off_trn, srt_trn, msg);
    gemm_dual<true, false><<<ggrid, 256, 0, stream>>>(msg, Wrel2, xa, Wroot2, b2, xb, N_NODES, HID);

    // conv3 x2: mean, connections
    aggregate_kernel<HID, true><<<N_NODES, HID, 0, stream>>>(xb, off_con, srt_con, msg);
    gemm_dual<true, true><<<ggrid, 256, 0, stream>>>(msg, Wrel3, xb, Wroot3, b3, xa, N_NODES, HID);
    aggregate_kernel<HID, true><<<N_NODES, HID, 0, stream>>>(xa, off_con, srt_con, msg);
    gemm_dual<true, true><<<ggrid, 256, 0, stream>>>(msg, Wrel3, xa, Wroot3, b3, xb, N_NODES, HID);

    // conv4: add, destinations
    aggregate_kernel<HID, false><<<N_NODES, HID, 0, stream>>>(xb, off_dst, srt_dst, msg);
    gemm_dual<true, true><<<ggrid, 256, 0, stream>>>(msg, Wrel4, xb, Wroot4, b4, xa, N_NODES, HID);

    // conv5 x2: add, connections
    aggregate_kernel<HID, false><<<N_NODES, HID, 0, stream>>>(xa, off_con, srt_con, msg);
    gemm_dual<true, true><<<ggrid, 256, 0, stream>>>(msg, Wrel5, xa, Wroot5, b5, xb, N_NODES, HID);
    aggregate_kernel<HID, false><<<N_NODES, HID, 0, stream>>>(xb, off_con, srt_con, msg);
    gemm_dual<true, true><<<ggrid, 256, 0, stream>>>(msg, Wrel5, xb, Wroot5, b5, xa, N_NODES, HID);

    // final linears (no relu)
    const float* WL0 = WL;                const float* bL0 = bL;
    const float* WL1 = WL + HID * HID;    const float* bL1 = bL + HID;
    gemm_dual<false, false><<<ggrid, 256, 0, stream>>>(xa, WL0, nullptr, nullptr, bL0, xb, N_NODES, HID);
    gemm_dual<false, false><<<ggrid, 256, 0, stream>>>(xb, WL1, nullptr, nullptr, bL1, outp, N_NODES, HID);
}

// Round 2
// 449.192 us; speedup vs baseline: 1.8573x; 1.8573x over previous
//
#include <hip/hip_runtime.h>
#include <hip/hip_bf16.h>

#define N_NODES 10000
#define HID 256
#define IN_F 128
#define E_CON 320000
#define E_DST 100000
#define E_TRN 50000

typedef __attribute__((ext_vector_type(8))) short short8v;
typedef __attribute__((ext_vector_type(4))) float f32x4;

__device__ __forceinline__ float b2f(unsigned int u) {
    return __uint_as_float(u << 16);
}
__device__ __forceinline__ unsigned short f2b(float f) {
    unsigned int u = __float_as_uint(f);
    unsigned int r = (u + 0x7fffu + ((u >> 16) & 1u)) >> 16;
    return (unsigned short)r;
}

// ---------------- CSR build ----------------

__global__ void hist_kernel(const int* __restrict__ dst, int nE, int* __restrict__ deg) {
    int i = blockIdx.x * blockDim.x + threadIdx.x;
    if (i < nE) atomicAdd(&deg[dst[i]], 1);
}

__global__ void scan_kernel(int* __restrict__ cur, int* __restrict__ off, int n) {
    __shared__ int smem[1024];
    __shared__ int running;
    if (threadIdx.x == 0) running = 0;
    __syncthreads();
    for (int base = 0; base < n; base += 1024) {
        int i = base + threadIdx.x;
        int v = (i < n) ? cur[i] : 0;
        smem[threadIdx.x] = v;
        __syncthreads();
        #pragma unroll
        for (int s = 1; s < 1024; s <<= 1) {
            int t = (threadIdx.x >= s) ? smem[threadIdx.x - s] : 0;
            __syncthreads();
            smem[threadIdx.x] += t;
            __syncthreads();
        }
        int incl = smem[threadIdx.x];
        int excl = incl - v + running;
        if (i < n) { off[i] = excl; cur[i] = excl; }
        __syncthreads();
        if (threadIdx.x == 1023) running += smem[1023];
        __syncthreads();
    }
    if (threadIdx.x == 0) off[n] = running;
}

__global__ void fill_kernel(const int* __restrict__ src, const int* __restrict__ dst,
                            int nE, int* __restrict__ cur, int* __restrict__ srt) {
    int i = blockIdx.x * blockDim.x + threadIdx.x;
    if (i < nE) {
        int p = atomicAdd(&cur[dst[i]], 1);
        srt[p] = src[i];
    }
}

// ---------------- conversions ----------------

__global__ void cvt_f32_bf16(const float* __restrict__ in, unsigned short* __restrict__ out, int n4) {
    int i = blockIdx.x * blockDim.x + threadIdx.x;
    if (i < n4) {
        float4 v = *(const float4*)&in[i * 4];
        ushort4 o;
        o.x = f2b(v.x); o.y = f2b(v.y); o.z = f2b(v.z); o.w = f2b(v.w);
        *(ushort4*)&out[i * 4] = o;
    }
}

// Pack W [K][256] fp32 -> Wp [K/32][256][32] bf16 with XOR-granule swizzle baked in:
// granule (kb, c, g') holds W rows kb*32 + (g'^((c>>1)&3))*8 .. +7, col c.
struct PackArgs {
    const float* W[12];
    unsigned short* O[12];
    int K[12];
};

__global__ void pack_weights(PackArgs pa) {
    int m = blockIdx.y;
    int K = pa.K[m];
    int granules = (K / 32) * 1024;
    int p = blockIdx.x * blockDim.x + threadIdx.x;
    if (p >= granules) return;
    int kb = p >> 10;
    int r  = p & 1023;
    int c  = r >> 2;
    int gp = r & 3;
    int g  = gp ^ ((c >> 1) & 3);
    const float* W = pa.W[m];
    unsigned short* O = pa.O[m] + (size_t)p * 8;
    int krow = kb * 32 + g * 8;
    ushort4 lo, hi;
    lo.x = f2b(W[(size_t)(krow + 0) * HID + c]);
    lo.y = f2b(W[(size_t)(krow + 1) * HID + c]);
    lo.z = f2b(W[(size_t)(krow + 2) * HID + c]);
    lo.w = f2b(W[(size_t)(krow + 3) * HID + c]);
    hi.x = f2b(W[(size_t)(krow + 4) * HID + c]);
    hi.y = f2b(W[(size_t)(krow + 5) * HID + c]);
    hi.z = f2b(W[(size_t)(krow + 6) * HID + c]);
    hi.w = f2b(W[(size_t)(krow + 7) * HID + c]);
    *(ushort4*)&O[0] = lo;
    *(ushort4*)&O[4] = hi;
}

// ---------------- aggregation (bf16 in, fp32 accum, bf16 out) ----------------

template <int F, bool MEAN>
__global__ __launch_bounds__(256) void agg_bf16(const unsigned short* __restrict__ xb,
                                                const int* __restrict__ off,
                                                const int* __restrict__ srt,
                                                unsigned short* __restrict__ msg) {
    constexpr int E = F / 64;   // elems per lane: 2 (F=128) or 4 (F=256)
    int w = threadIdx.x >> 6;
    int lane = threadIdx.x & 63;
    int node = blockIdx.x * 4 + w;
    int s0 = off[node], s1 = off[node + 1];
    float a0 = 0.f, a1 = 0.f, a2 = 0.f, a3 = 0.f;
    const unsigned short* colbase = xb + lane * E;
    int e = s0;
    for (; e + 1 < s1; e += 2) {
        int sA = srt[e], sB = srt[e + 1];
        if constexpr (E == 4) {
            ushort4 vA = *(const ushort4*)(colbase + (size_t)sA * F);
            ushort4 vB = *(const ushort4*)(colbase + (size_t)sB * F);
            a0 += b2f(vA.x) + b2f(vB.x);
            a1 += b2f(vA.y) + b2f(vB.y);
            a2 += b2f(vA.z) + b2f(vB.z);
            a3 += b2f(vA.w) + b2f(vB.w);
        } else {
            unsigned int vA = *(const unsigned int*)(colbase + (size_t)sA * F);
            unsigned int vB = *(const unsigned int*)(colbase + (size_t)sB * F);
            a0 += b2f(vA & 0xffffu) + b2f(vB & 0xffffu);
            a1 += b2f(vA >> 16) + b2f(vB >> 16);
        }
    }
    if (e < s1) {
        int sA = srt[e];
        if constexpr (E == 4) {
            ushort4 vA = *(const ushort4*)(colbase + (size_t)sA * F);
            a0 += b2f(vA.x); a1 += b2f(vA.y); a2 += b2f(vA.z); a3 += b2f(vA.w);
        } else {
            unsigned int vA = *(const unsigned int*)(colbase + (size_t)sA * F);
            a0 += b2f(vA & 0xffffu); a1 += b2f(vA >> 16);
        }
    }
    if (MEAN) {
        float inv = 1.f / fmaxf((float)(s1 - s0), 1.f);
        a0 *= inv; a1 *= inv; a2 *= inv; a3 *= inv;
    }
    unsigned short* op = msg + (size_t)node * F + lane * E;
    if constexpr (E == 4) {
        ushort4 o; o.x = f2b(a0); o.y = f2b(a1); o.z = f2b(a2); o.w = f2b(a3);
        *(ushort4*)op = o;
    } else {
        unsigned int o = (unsigned int)f2b(a0) | ((unsigned int)f2b(a1) << 16);
        *(unsigned int*)op = o;
    }
}

// ---------------- MFMA GEMM ----------------
// out = A1 @ W1 (+ A2 @ W2) + bias, optional relu.
// A: [M][K] bf16 row-major. Wp: packed [K/32][256][32] bf16 (swizzled).
// Block: 256 threads = 4 waves (2x2), block tile 64 rows x 128 cols, grid (ceil(M/64), 2).

#define GLOAD_LDS16(g, l) __builtin_amdgcn_global_load_lds( \
    (const __attribute__((address_space(1))) unsigned int*)(g), \
    (__attribute__((address_space(3))) unsigned int*)(l), 16, 0, 0)

template <int K, bool DUAL, bool RELU, bool OUT32>
__global__ __launch_bounds__(256) void gemm_mfma(const unsigned short* __restrict__ A1,
                                                 const unsigned short* __restrict__ Wp1,
                                                 const unsigned short* __restrict__ A2,
                                                 const unsigned short* __restrict__ Wp2,
                                                 const float* __restrict__ bias,
                                                 unsigned short* __restrict__ outb,
                                                 float* __restrict__ outf, int M) {
    constexpr int KB = K / 32;
    constexpr int NT = DUAL ? 2 * KB : KB;
    __shared__ unsigned short As[2][64 * 32];    // 4 KB per buf
    __shared__ unsigned short Bs[2][128 * 32];   // 8 KB per buf
    const int tid = threadIdx.x;
    const int lane = tid & 63;
    const int w = tid >> 6;
    const int wr = w >> 1, wc = w & 1;
    const int row0 = blockIdx.x * 64;
    const int colblk = blockIdx.y;

    f32x4 acc[2][4] = {};

    auto stage = [&](int buf, int t) {
        int pass = DUAL ? (t / KB) : 0;
        int kb = DUAL ? (t % KB) : t;
        const unsigned short* A = pass ? A2 : A1;
        const unsigned short* Wp = pass ? Wp2 : Wp1;
        // A tile: 64 rows x 32 k (4 KB), one call; swizzle applied on SOURCE addr.
        {
            int row_l = tid >> 2, gp = tid & 3;
            int gs = gp ^ ((row_l >> 1) & 3);
            int row_g = row0 + row_l;
            if (row_g > M - 1) row_g = M - 1;
            const unsigned short* src = A + (size_t)row_g * K + kb * 32 + gs * 8;
            GLOAD_LDS16(src, &As[buf][w * 512]);
        }
        // B tile: 128 cols x 32 k (8 KB), two calls; Wp already swizzle-packed -> linear.
        {
            const unsigned short* base = Wp + (size_t)kb * 8192 + (size_t)colblk * 4096;
            GLOAD_LDS16(base + tid * 8,        &Bs[buf][w * 512]);
            GLOAD_LDS16(base + 2048 + tid * 8, &Bs[buf][2048 + w * 512]);
        }
    };

    auto compute = [&](int buf) {
        short8v a[2], b[4];
        const int g = lane >> 4;
        #pragma unroll
        for (int rf = 0; rf < 2; ++rf) {
            int row_l = wr * 32 + rf * 16 + (lane & 15);
            int q = g ^ ((row_l >> 1) & 3);
            a[rf] = *(const short8v*)&As[buf][row_l * 32 + q * 8];
        }
        #pragma unroll
        for (int cf = 0; cf < 4; ++cf) {
            int col_l = wc * 64 + cf * 16 + (lane & 15);
            int q = g ^ ((col_l >> 1) & 3);
            b[cf] = *(const short8v*)&Bs[buf][col_l * 32 + q * 8];
        }
        #pragma unroll
        for (int cf = 0; cf < 4; ++cf)
            #pragma unroll
            for (int rf = 0; rf < 2; ++rf)
                acc[rf][cf] = __builtin_amdgcn_mfma_f32_16x16x32_bf16(a[rf], b[cf], acc[rf][cf], 0, 0, 0);
    };

    stage(0, 0);
    __syncthreads();
    int buf = 0;
    for (int t = 0; t < NT; ++t) {
        if (t + 1 < NT) stage(buf ^ 1, t + 1);
        compute(buf);
        __syncthreads();
        buf ^= 1;
    }

    // epilogue
    #pragma unroll
    for (int cf = 0; cf < 4; ++cf) {
        int c = colblk * 128 + wc * 64 + cf * 16 + (lane & 15);
        float bv = bias[c];
        #pragma unroll
        for (int rf = 0; rf < 2; ++rf) {
            #pragma unroll
            for (int i = 0; i < 4; ++i) {
                int r = row0 + wr * 32 + rf * 16 + (lane >> 4) * 4 + i;
                if (r < M) {
                    float v = acc[rf][cf][i] + bv;
                    if (RELU) v = fmaxf(v, 0.f);
                    if (OUT32) outf[(size_t)r * HID + c] = v;
                    else       outb[(size_t)r * HID + c] = f2b(v);
                }
            }
        }
    }
}

// ---------------- launch ----------------

static inline char* align256(char* p) {
    return (char*)(((uintptr_t)p + 255) & ~(uintptr_t)255);
}

extern "C" void kernel_launch(void* const* d_in, const int* in_sizes, int n_in,
                              void* d_out, int out_size, void* d_ws, size_t ws_size,
                              hipStream_t stream) {
    const float* x0     = (const float*)d_in[0];
    const int*   ei_con = (const int*)d_in[1];
    const int*   ei_dst = (const int*)d_in[2];
    const int*   ei_trn = (const int*)d_in[3];
    const float* Wmat[12] = {
        (const float*)d_in[5],  (const float*)d_in[4],    // Wrel1, Wroot1 (K=128)
        (const float*)d_in[8],  (const float*)d_in[7],    // Wrel2, Wroot2
        (const float*)d_in[11], (const float*)d_in[10],   // Wrel3, Wroot3
        (const float*)d_in[14], (const float*)d_in[13],   // Wrel4, Wroot4
        (const float*)d_in[17], (const float*)d_in[16],   // Wrel5, Wroot5
        (const float*)d_in[19],                            // WL0
        (const float*)d_in[19] + HID * HID                 // WL1
    };
    const float* b1 = (const float*)d_in[6];
    const float* b2 = (const float*)d_in[9];
    const float* b3 = (const float*)d_in[12];
    const float* b4 = (const float*)d_in[15];
    const float* b5 = (const float*)d_in[18];
    const float* bL = (const float*)d_in[20];

    const int eCon = in_sizes[1] / 2;
    const int eDst = in_sizes[2] / 2;
    const int eTrn = in_sizes[3] / 2;
    const int* src_con = ei_con;  const int* dst_con = ei_con + eCon;
    const int* src_dst = ei_dst;  const int* dst_dst = ei_dst + eDst;
    const int* src_trn = ei_trn;  const int* dst_trn = ei_trn + eTrn;

    char* p = (char*)d_ws;
    int* off_con = (int*)p; p = align256(p + (N_NODES + 1) * 4);
    int* cur_con = (int*)p; p = align256(p + N_NODES * 4);
    int* off_dst = (int*)p; p = align256(p + (N_NODES + 1) * 4);
    int* cur_dst = (int*)p; p = align256(p + N_NODES * 4);
    int* off_trn = (int*)p; p = align256(p + (N_NODES + 1) * 4);
    int* cur_trn = (int*)p; p = align256(p + N_NODES * 4);
    int* srt_con = (int*)p; p = align256(p + E_CON * 4);
    int* srt_dst = (int*)p; p = align256(p + E_DST * 4);
    int* srt_trn = (int*)p; p = align256(p + E_TRN * 4);
    unsigned short* x0b  = (unsigned short*)p; p = align256(p + (size_t)N_NODES * IN_F * 2);
    unsigned short* msgb = (unsigned short*)p; p = align256(p + (size_t)N_NODES * HID * 2);
    unsigned short* xab  = (unsigned short*)p; p = align256(p + (size_t)N_NODES * HID * 2);
    unsigned short* xbb  = (unsigned short*)p; p = align256(p + (size_t)N_NODES * HID * 2);
    unsigned short* WpBuf[12];
    PackArgs pa;
    for (int m = 0; m < 12; ++m) {
        int K = (m < 2) ? IN_F : HID;
        WpBuf[m] = (unsigned short*)p; p = align256(p + (size_t)K * HID * 2);
        pa.W[m] = Wmat[m];
        pa.O[m] = WpBuf[m];
        pa.K[m] = K;
    }
    float* outp = (float*)d_out;

    // ---- weight pack + x0 conversion ----
    pack_weights<<<dim3(32, 12), 256, 0, stream>>>(pa);
    cvt_f32_bf16<<<(N_NODES * IN_F / 4 + 255) / 256, 256, 0, stream>>>(x0, x0b, N_NODES * IN_F / 4);

    // ---- CSR build ----
    hipMemsetAsync(cur_con, 0, N_NODES * 4, stream);
    hipMemsetAsync(cur_dst, 0, N_NODES * 4, stream);
    hipMemsetAsync(cur_trn, 0, N_NODES * 4, stream);
    hist_kernel<<<(eCon + 255) / 256, 256, 0, stream>>>(dst_con, eCon, cur_con);
    hist_kernel<<<(eDst + 255) / 256, 256, 0, stream>>>(dst_dst, eDst, cur_dst);
    hist_kernel<<<(eTrn + 255) / 256, 256, 0, stream>>>(dst_trn, eTrn, cur_trn);
    scan_kernel<<<1, 1024, 0, stream>>>(cur_con, off_con, N_NODES);
    scan_kernel<<<1, 1024, 0, stream>>>(cur_dst, off_dst, N_NODES);
    scan_kernel<<<1, 1024, 0, stream>>>(cur_trn, off_trn, N_NODES);
    fill_kernel<<<(eCon + 255) / 256, 256, 0, stream>>>(src_con, dst_con, eCon, cur_con, srt_con);
    fill_kernel<<<(eDst + 255) / 256, 256, 0, stream>>>(src_dst, dst_dst, eDst, cur_dst, srt_dst);
    fill_kernel<<<(eTrn + 255) / 256, 256, 0, stream>>>(src_trn, dst_trn, eTrn, cur_trn, srt_trn);

    dim3 ggrid((N_NODES + 63) / 64, 2);
    const int agrid = N_NODES / 4;

    // conv1: relu(msg@Wrel1 + x0@Wroot1 + b1), connections, K=128
    agg_bf16<IN_F, false><<<agrid, 256, 0, stream>>>(x0b, off_con, srt_con, msgb);
    gemm_mfma<IN_F, true, true, false><<<ggrid, 256, 0, stream>>>(msgb, WpBuf[0], x0b, WpBuf[1], b1, xab, nullptr, N_NODES);

    // conv2: (no relu), trains
    agg_bf16<HID, false><<<agrid, 256, 0, stream>>>(xab, off_trn, srt_trn, msgb);
    gemm_mfma<HID, true, false, false><<<ggrid, 256, 0, stream>>>(msgb, WpBuf[2], xab, WpBuf[3], b2, xbb, nullptr, N_NODES);

    // conv3 x2: relu, mean, connections
    agg_bf16<HID, true><<<agrid, 256, 0, stream>>>(xbb, off_con, srt_con, msgb);
    gemm_mfma<HID, true, true, false><<<ggrid, 256, 0, stream>>>(msgb, WpBuf[4], xbb, WpBuf[5], b3, xab, nullptr, N_NODES);
    agg_bf16<HID, true><<<agrid, 256, 0, stream>>>(xab, off_con, srt_con, msgb);
    gemm_mfma<HID, true, true, false><<<ggrid, 256, 0, stream>>>(msgb, WpBuf[4], xab, WpBuf[5], b3, xbb, nullptr, N_NODES);

    // conv4: relu, add, destinations
    agg_bf16<HID, false><<<agrid, 256, 0, stream>>>(xbb, off_dst, srt_dst, msgb);
    gemm_mfma<HID, true, true, false><<<ggrid, 256, 0, stream>>>(msgb, WpBuf[6], xbb, WpBuf[7], b4, xab, nullptr, N_NODES);

    // conv5 x2: relu, add, connections
    agg_bf16<HID, false><<<agrid, 256, 0, stream>>>(xab, off_con, srt_con, msgb);
    gemm_mfma<HID, true, true, false><<<ggrid, 256, 0, stream>>>(msgb, WpBuf[8], xab, WpBuf[9], b5, xbb, nullptr, N_NODES);
    agg_bf16<HID, false><<<agrid, 256, 0, stream>>>(xbb, off_con, srt_con, msgb);
    gemm_mfma<HID, true, true, false><<<ggrid, 256, 0, stream>>>(msgb, WpBuf[8], xbb, WpBuf[9], b5, xab, nullptr, N_NODES);

    // final linears
    gemm_mfma<HID, false, false, false><<<ggrid, 256, 0, stream>>>(xab, WpBuf[10], nullptr, nullptr, bL, xbb, nullptr, N_NODES);
    gemm_mfma<HID, false, false, true><<<ggrid, 256, 0, stream>>>(xbb, WpBuf[11], nullptr, nullptr, bL + HID, nullptr, outp, N_NODES);
}

// Round 3
// 340.082 us; speedup vs baseline: 2.4532x; 1.3208x over previous
//
#include <hip/hip_runtime.h>
#include <hip/hip_bf16.h>

#define N_NODES 10000
#define HID 256
#define IN_F 128
#define E_CON 320000
#define E_DST 100000
#define E_TRN 50000

typedef __attribute__((ext_vector_type(8))) short short8v;
typedef __attribute__((ext_vector_type(4))) float f32x4;

__device__ __forceinline__ float b2f(unsigned int u) {
    return __uint_as_float(u << 16);
}
__device__ __forceinline__ unsigned short f2b(float f) {
    unsigned int u = __float_as_uint(f);
    unsigned int r = (u + 0x7fffu + ((u >> 16) & 1u)) >> 16;
    return (unsigned short)r;
}

// ---------------- CSR build (fused, 3 graphs) ----------------

struct GraphDesc {
    const int* src;
    const int* dst;
    int nE;
    int* cur;   // cursor / degree scratch
    int* off;   // [N_NODES+1]
    int* srt;   // sorted-by-dest sources
};
struct CsrArgs { GraphDesc g[3]; };

__global__ void hist3(CsrArgs a) {
    const GraphDesc& gg = a.g[blockIdx.y];
    int i = blockIdx.x * blockDim.x + threadIdx.x;
    if (i < gg.nE) atomicAdd(&gg.cur[gg.dst[i]], 1);
}

__global__ void fill3(CsrArgs a) {
    const GraphDesc& gg = a.g[blockIdx.y];
    int i = blockIdx.x * blockDim.x + threadIdx.x;
    if (i < gg.nE) {
        int p = atomicAdd(&gg.cur[gg.dst[i]], 1);
        gg.srt[p] = gg.src[i];
    }
}

// One block per graph, 1024 threads, shfl-based scan (exclusive) over N_NODES.
__global__ __launch_bounds__(1024) void scan3(CsrArgs a) {
    const GraphDesc& gg = a.g[blockIdx.x];
    int* cur = gg.cur;
    int* off = gg.off;
    const int n = N_NODES;
    __shared__ int wsum[16];
    __shared__ int wtot;
    __shared__ int carry_sh;
    int tid = threadIdx.x;
    int lane = tid & 63;
    int w = tid >> 6;
    if (tid == 0) carry_sh = 0;
    __syncthreads();
    for (int base = 0; base < n; base += 1024) {
        int i = base + tid;
        int v = (i < n) ? cur[i] : 0;
        // inclusive wave scan
        int s = v;
        #pragma unroll
        for (int d = 1; d < 64; d <<= 1) {
            int t = __shfl_up(s, d, 64);
            if (lane >= d) s += t;
        }
        if (lane == 63) wsum[w] = s;
        __syncthreads();
        if (w == 0 && lane < 16) {
            int t = wsum[lane];
            int ss = t;
            #pragma unroll
            for (int d = 1; d < 16; d <<= 1) {
                int u = __shfl_up(ss, d, 64);
                if (lane >= d) ss += u;
            }
            wsum[lane] = ss - t;       // exclusive wave offset
            if (lane == 15) wtot = ss; // chunk total
        }
        __syncthreads();
        int carry = carry_sh;
        int excl = s - v + wsum[w] + carry;
        if (i < n) { off[i] = excl; cur[i] = excl; }
        __syncthreads();
        if (tid == 0) carry_sh += wtot;
        __syncthreads();
    }
    if (threadIdx.x == 0) off[n] = carry_sh;
}

// ---------------- conversions ----------------

__global__ void cvt_f32_bf16(const float* __restrict__ in, unsigned short* __restrict__ out, int n4) {
    int i = blockIdx.x * blockDim.x + threadIdx.x;
    if (i < n4) {
        float4 v = *(const float4*)&in[i * 4];
        ushort4 o;
        o.x = f2b(v.x); o.y = f2b(v.y); o.z = f2b(v.z); o.w = f2b(v.w);
        *(ushort4*)&out[i * 4] = o;
    }
}

// Pack W [K][256] fp32 -> Wp [K/32][256][32] bf16 with XOR-granule swizzle baked in.
struct PackArgs {
    const float* W[12];
    unsigned short* O[12];
    int K[12];
};

__global__ void pack_weights(PackArgs pa) {
    int m = blockIdx.y;
    int K = pa.K[m];
    int granules = (K / 32) * 1024;
    int p = blockIdx.x * blockDim.x + threadIdx.x;
    if (p >= granules) return;
    int kb = p >> 10;
    int r  = p & 1023;
    int c  = r >> 2;
    int gp = r & 3;
    int g  = gp ^ ((c >> 1) & 3);
    const float* W = pa.W[m];
    unsigned short* O = pa.O[m] + (size_t)p * 8;
    int krow = kb * 32 + g * 8;
    ushort4 lo, hi;
    lo.x = f2b(W[(size_t)(krow + 0) * HID + c]);
    lo.y = f2b(W[(size_t)(krow + 1) * HID + c]);
    lo.z = f2b(W[(size_t)(krow + 2) * HID + c]);
    lo.w = f2b(W[(size_t)(krow + 3) * HID + c]);
    hi.x = f2b(W[(size_t)(krow + 4) * HID + c]);
    hi.y = f2b(W[(size_t)(krow + 5) * HID + c]);
    hi.z = f2b(W[(size_t)(krow + 6) * HID + c]);
    hi.w = f2b(W[(size_t)(krow + 7) * HID + c]);
    *(ushort4*)&O[0] = lo;
    *(ushort4*)&O[4] = hi;
}

// ---------------- aggregation (bf16 in, fp32 accum, bf16 out) ----------------

template <int F, bool MEAN>
__global__ __launch_bounds__(256) void agg_bf16(const unsigned short* __restrict__ xb,
                                                const int* __restrict__ off,
                                                const int* __restrict__ srt,
                                                unsigned short* __restrict__ msg) {
    constexpr int E = F / 64;   // elems per lane: 2 (F=128) or 4 (F=256)
    int w = threadIdx.x >> 6;
    int lane = threadIdx.x & 63;
    int node = blockIdx.x * 4 + w;
    int s0 = off[node], s1 = off[node + 1];
    float a0 = 0.f, a1 = 0.f, a2 = 0.f, a3 = 0.f;
    const unsigned short* colbase = xb + lane * E;
    int e = s0;
    for (; e + 3 < s1; e += 4) {
        int sA = srt[e], sB = srt[e + 1], sC = srt[e + 2], sD = srt[e + 3];
        if constexpr (E == 4) {
            ushort4 vA = *(const ushort4*)(colbase + (size_t)sA * F);
            ushort4 vB = *(const ushort4*)(colbase + (size_t)sB * F);
            ushort4 vC = *(const ushort4*)(colbase + (size_t)sC * F);
            ushort4 vD = *(const ushort4*)(colbase + (size_t)sD * F);
            a0 += (b2f(vA.x) + b2f(vB.x)) + (b2f(vC.x) + b2f(vD.x));
            a1 += (b2f(vA.y) + b2f(vB.y)) + (b2f(vC.y) + b2f(vD.y));
            a2 += (b2f(vA.z) + b2f(vB.z)) + (b2f(vC.z) + b2f(vD.z));
            a3 += (b2f(vA.w) + b2f(vB.w)) + (b2f(vC.w) + b2f(vD.w));
        } else {
            unsigned int vA = *(const unsigned int*)(colbase + (size_t)sA * F);
            unsigned int vB = *(const unsigned int*)(colbase + (size_t)sB * F);
            unsigned int vC = *(const unsigned int*)(colbase + (size_t)sC * F);
            unsigned int vD = *(const unsigned int*)(colbase + (size_t)sD * F);
            a0 += (b2f(vA & 0xffffu) + b2f(vB & 0xffffu)) + (b2f(vC & 0xffffu) + b2f(vD & 0xffffu));
            a1 += (b2f(vA >> 16) + b2f(vB >> 16)) + (b2f(vC >> 16) + b2f(vD >> 16));
        }
    }
    for (; e < s1; ++e) {
        int sA = srt[e];
        if constexpr (E == 4) {
            ushort4 vA = *(const ushort4*)(colbase + (size_t)sA * F);
            a0 += b2f(vA.x); a1 += b2f(vA.y); a2 += b2f(vA.z); a3 += b2f(vA.w);
        } else {
            unsigned int vA = *(const unsigned int*)(colbase + (size_t)sA * F);
            a0 += b2f(vA & 0xffffu); a1 += b2f(vA >> 16);
        }
    }
    if (MEAN) {
        float inv = 1.f / fmaxf((float)(s1 - s0), 1.f);
        a0 *= inv; a1 *= inv; a2 *= inv; a3 *= inv;
    }
    unsigned short* op = msg + (size_t)node * F + lane * E;
    if constexpr (E == 4) {
        ushort4 o; o.x = f2b(a0); o.y = f2b(a1); o.z = f2b(a2); o.w = f2b(a3);
        *(ushort4*)op = o;
    } else {
        unsigned int o = (unsigned int)f2b(a0) | ((unsigned int)f2b(a1) << 16);
        *(unsigned int*)op = o;
    }
}

// ---------------- MFMA GEMM ----------------
// out = A1 @ W1 (+ A2 @ W2) + bias, optional relu.
// A: [M][K] bf16 row-major. Wp: packed [K/32][256][32] bf16 (swizzled).
// Block: 256 threads = 4 waves (2x2), block tile 64 rows x 128 cols, grid (ceil(M/64), 2).

#define GLOAD_LDS16(g, l) __builtin_amdgcn_global_load_lds( \
    (const __attribute__((address_space(1))) unsigned int*)(g), \
    (__attribute__((address_space(3))) unsigned int*)(l), 16, 0, 0)

template <int K, bool DUAL, bool RELU, bool OUT32>
__global__ __launch_bounds__(256) void gemm_mfma(const unsigned short* __restrict__ A1,
                                                 const unsigned short* __restrict__ Wp1,
                                                 const unsigned short* __restrict__ A2,
                                                 const unsigned short* __restrict__ Wp2,
                                                 const float* __restrict__ bias,
                                                 unsigned short* __restrict__ outb,
                                                 float* __restrict__ outf, int M) {
    constexpr int KB = K / 32;
    constexpr int NT = DUAL ? 2 * KB : KB;
    __shared__ unsigned short As[2][64 * 32];    // 4 KB per buf
    __shared__ unsigned short Bs[2][128 * 32];   // 8 KB per buf
    const int tid = threadIdx.x;
    const int lane = tid & 63;
    const int w = tid >> 6;
    const int wr = w >> 1, wc = w & 1;
    const int row0 = blockIdx.x * 64;
    const int colblk = blockIdx.y;

    f32x4 acc[2][4] = {};

    auto stage = [&](int buf, int t) {
        int pass = DUAL ? (t / KB) : 0;
        int kb = DUAL ? (t % KB) : t;
        const unsigned short* A = pass ? A2 : A1;
        const unsigned short* Wp = pass ? Wp2 : Wp1;
        {
            int row_l = tid >> 2, gp = tid & 3;
            int gs = gp ^ ((row_l >> 1) & 3);
            int row_g = row0 + row_l;
            if (row_g > M - 1) row_g = M - 1;
            const unsigned short* src = A + (size_t)row_g * K + kb * 32 + gs * 8;
            GLOAD_LDS16(src, &As[buf][w * 512]);
        }
        {
            const unsigned short* base = Wp + (size_t)kb * 8192 + (size_t)colblk * 4096;
            GLOAD_LDS16(base + tid * 8,        &Bs[buf][w * 512]);
            GLOAD_LDS16(base + 2048 + tid * 8, &Bs[buf][2048 + w * 512]);
        }
    };

    auto compute = [&](int buf) {
        short8v a[2], b[4];
        const int g = lane >> 4;
        #pragma unroll
        for (int rf = 0; rf < 2; ++rf) {
            int row_l = wr * 32 + rf * 16 + (lane & 15);
            int q = g ^ ((row_l >> 1) & 3);
            a[rf] = *(const short8v*)&As[buf][row_l * 32 + q * 8];
        }
        #pragma unroll
        for (int cf = 0; cf < 4; ++cf) {
            int col_l = wc * 64 + cf * 16 + (lane & 15);
            int q = g ^ ((col_l >> 1) & 3);
            b[cf] = *(const short8v*)&Bs[buf][col_l * 32 + q * 8];
        }
        #pragma unroll
        for (int cf = 0; cf < 4; ++cf)
            #pragma unroll
            for (int rf = 0; rf < 2; ++rf)
                acc[rf][cf] = __builtin_amdgcn_mfma_f32_16x16x32_bf16(a[rf], b[cf], acc[rf][cf], 0, 0, 0);
    };

    stage(0, 0);
    __syncthreads();
    int buf = 0;
    for (int t = 0; t < NT; ++t) {
        if (t + 1 < NT) stage(buf ^ 1, t + 1);
        compute(buf);
        __syncthreads();
        buf ^= 1;
    }

    #pragma unroll
    for (int cf = 0; cf < 4; ++cf) {
        int c = colblk * 128 + wc * 64 + cf * 16 + (lane & 15);
        float bv = bias[c];
        #pragma unroll
        for (int rf = 0; rf < 2; ++rf) {
            #pragma unroll
            for (int i = 0; i < 4; ++i) {
                int r = row0 + wr * 32 + rf * 16 + (lane >> 4) * 4 + i;
                if (r < M) {
                    float v = acc[rf][cf][i] + bv;
                    if (RELU) v = fmaxf(v, 0.f);
                    if (OUT32) outf[(size_t)r * HID + c] = v;
                    else       outb[(size_t)r * HID + c] = f2b(v);
                }
            }
        }
    }
}

// ---------------- launch ----------------

static inline char* align256(char* p) {
    return (char*)(((uintptr_t)p + 255) & ~(uintptr_t)255);
}

extern "C" void kernel_launch(void* const* d_in, const int* in_sizes, int n_in,
                              void* d_out, int out_size, void* d_ws, size_t ws_size,
                              hipStream_t stream) {
    const float* x0     = (const float*)d_in[0];
    const int*   ei_con = (const int*)d_in[1];
    const int*   ei_dst = (const int*)d_in[2];
    const int*   ei_trn = (const int*)d_in[3];
    const float* Wmat[12] = {
        (const float*)d_in[5],  (const float*)d_in[4],    // Wrel1, Wroot1 (K=128)
        (const float*)d_in[8],  (const float*)d_in[7],
        (const float*)d_in[11], (const float*)d_in[10],
        (const float*)d_in[14], (const float*)d_in[13],
        (const float*)d_in[17], (const float*)d_in[16],
        (const float*)d_in[19],
        (const float*)d_in[19] + HID * HID
    };
    const float* b1 = (const float*)d_in[6];
    const float* b2 = (const float*)d_in[9];
    const float* b3 = (const float*)d_in[12];
    const float* b4 = (const float*)d_in[15];
    const float* b5 = (const float*)d_in[18];
    const float* bL = (const float*)d_in[20];

    const int eCon = in_sizes[1] / 2;
    const int eDst = in_sizes[2] / 2;
    const int eTrn = in_sizes[3] / 2;

    char* p = (char*)d_ws;
    int* cur_all  = (int*)p; p = align256(p + 3 * N_NODES * 4);      // contiguous: one memset
    int* off_con = (int*)p; p = align256(p + (N_NODES + 1) * 4);
    int* off_dst = (int*)p; p = align256(p + (N_NODES + 1) * 4);
    int* off_trn = (int*)p; p = align256(p + (N_NODES + 1) * 4);
    int* srt_con = (int*)p; p = align256(p + E_CON * 4);
    int* srt_dst = (int*)p; p = align256(p + E_DST * 4);
    int* srt_trn = (int*)p; p = align256(p + E_TRN * 4);
    unsigned short* x0b  = (unsigned short*)p; p = align256(p + (size_t)N_NODES * IN_F * 2);
    unsigned short* msgb = (unsigned short*)p; p = align256(p + (size_t)N_NODES * HID * 2);
    unsigned short* xab  = (unsigned short*)p; p = align256(p + (size_t)N_NODES * HID * 2);
    unsigned short* xbb  = (unsigned short*)p; p = align256(p + (size_t)N_NODES * HID * 2);
    unsigned short* WpBuf[12];
    PackArgs pa;
    for (int m = 0; m < 12; ++m) {
        int K = (m < 2) ? IN_F : HID;
        WpBuf[m] = (unsigned short*)p; p = align256(p + (size_t)K * HID * 2);
        pa.W[m] = Wmat[m];
        pa.O[m] = WpBuf[m];
        pa.K[m] = K;
    }
    float* outp = (float*)d_out;

    CsrArgs ca;
    ca.g[0] = { ei_con, ei_con + eCon, eCon, cur_all,              off_con, srt_con };
    ca.g[1] = { ei_dst, ei_dst + eDst, eDst, cur_all + N_NODES,    off_dst, srt_dst };
    ca.g[2] = { ei_trn, ei_trn + eTrn, eTrn, cur_all + 2*N_NODES,  off_trn, srt_trn };

    // ---- weight pack + x0 conversion ----
    pack_weights<<<dim3(32, 12), 256, 0, stream>>>(pa);
    cvt_f32_bf16<<<(N_NODES * IN_F / 4 + 255) / 256, 256, 0, stream>>>(x0, x0b, N_NODES * IN_F / 4);

    // ---- CSR build ----
    hipMemsetAsync(cur_all, 0, 3 * N_NODES * 4, stream);
    dim3 hgrid((eCon + 255) / 256, 3);
    hist3<<<hgrid, 256, 0, stream>>>(ca);
    scan3<<<3, 1024, 0, stream>>>(ca);
    fill3<<<hgrid, 256, 0, stream>>>(ca);

    dim3 ggrid((N_NODES + 63) / 64, 2);
    const int agrid = N_NODES / 4;

    // conv1: relu(msg@Wrel1 + x0@Wroot1 + b1), connections, K=128
    agg_bf16<IN_F, false><<<agrid, 256, 0, stream>>>(x0b, off_con, srt_con, msgb);
    gemm_mfma<IN_F, true, true, false><<<ggrid, 256, 0, stream>>>(msgb, WpBuf[0], x0b, WpBuf[1], b1, xab, nullptr, N_NODES);

    // conv2: (no relu), trains
    agg_bf16<HID, false><<<agrid, 256, 0, stream>>>(xab, off_trn, srt_trn, msgb);
    gemm_mfma<HID, true, false, false><<<ggrid, 256, 0, stream>>>(msgb, WpBuf[2], xab, WpBuf[3], b2, xbb, nullptr, N_NODES);

    // conv3 x2: relu, mean, connections
    agg_bf16<HID, true><<<agrid, 256, 0, stream>>>(xbb, off_con, srt_con, msgb);
    gemm_mfma<HID, true, true, false><<<ggrid, 256, 0, stream>>>(msgb, WpBuf[4], xbb, WpBuf[5], b3, xab, nullptr, N_NODES);
    agg_bf16<HID, true><<<agrid, 256, 0, stream>>>(xab, off_con, srt_con, msgb);
    gemm_mfma<HID, true, true, false><<<ggrid, 256, 0, stream>>>(msgb, WpBuf[4], xab, WpBuf[5], b3, xbb, nullptr, N_NODES);

    // conv4: relu, add, destinations
    agg_bf16<HID, false><<<agrid, 256, 0, stream>>>(xbb, off_dst, srt_dst, msgb);
    gemm_mfma<HID, true, true, false><<<ggrid, 256, 0, stream>>>(msgb, WpBuf[6], xbb, WpBuf[7], b4, xab, nullptr, N_NODES);

    // conv5 x2: relu, add, connections
    agg_bf16<HID, false><<<agrid, 256, 0, stream>>>(xab, off_con, srt_con, msgb);
    gemm_mfma<HID, true, true, false><<<ggrid, 256, 0, stream>>>(msgb, WpBuf[8], xab, WpBuf[9], b5, xbb, nullptr, N_NODES);
    agg_bf16<HID, false><<<agrid, 256, 0, stream>>>(xbb, off_con, srt_con, msgb);
    gemm_mfma<HID, true, true, false><<<ggrid, 256, 0, stream>>>(msgb, WpBuf[8], xbb, WpBuf[9], b5, xab, nullptr, N_NODES);

    // final linears
    gemm_mfma<HID, false, false, false><<<ggrid, 256, 0, stream>>>(xab, WpBuf[10], nullptr, nullptr, bL, xbb, nullptr, N_NODES);
    gemm_mfma<HID, false, false, true><<<ggrid, 256, 0, stream>>>(xbb, WpBuf[11], nullptr, nullptr, bL + HID, nullptr, outp, N_NODES);
}

// Round 4
// 310.092 us; speedup vs baseline: 2.6905x; 1.0967x over previous
//
#include <hip/hip_runtime.h>
#include <hip/hip_bf16.h>

#define N_NODES 10000
#define HID 256
#define IN_F 128
#define E_CON 320000
#define E_DST 100000
#define E_TRN 50000

typedef __attribute__((ext_vector_type(8))) short short8v;
typedef __attribute__((ext_vector_type(4))) float f32x4;

__device__ __forceinline__ float b2f(unsigned int u) {
    return __uint_as_float(u << 16);
}
__device__ __forceinline__ unsigned short f2b(float f) {
    unsigned int u = __float_as_uint(f);
    unsigned int r = (u + 0x7fffu + ((u >> 16) & 1u)) >> 16;
    return (unsigned short)r;
}

// ---------------- CSR build (fused, 3 graphs) ----------------

struct GraphDesc {
    const int* src;
    const int* dst;
    int nE;
    int* cur;
    int* off;
    int* srt;
};
struct CsrArgs { GraphDesc g[3]; };

__global__ void zero_cur(int* __restrict__ cur) {
    int i = blockIdx.x * blockDim.x + threadIdx.x;
    if (i < 3 * N_NODES) cur[i] = 0;
}

__global__ void hist3(CsrArgs a) {
    const GraphDesc& gg = a.g[blockIdx.y];
    int i = blockIdx.x * blockDim.x + threadIdx.x;
    if (i < gg.nE) atomicAdd(&gg.cur[gg.dst[i]], 1);
}

__global__ void fill3(CsrArgs a) {
    const GraphDesc& gg = a.g[blockIdx.y];
    int i = blockIdx.x * blockDim.x + threadIdx.x;
    if (i < gg.nE) {
        int p = atomicAdd(&gg.cur[gg.dst[i]], 1);
        gg.srt[p] = gg.src[i];
    }
}

// One block per graph, 1024 threads, shfl-based exclusive scan over N_NODES.
__global__ __launch_bounds__(1024) void scan3(CsrArgs a) {
    const GraphDesc& gg = a.g[blockIdx.x];
    int* cur = gg.cur;
    int* off = gg.off;
    const int n = N_NODES;
    __shared__ int wsum[16];
    __shared__ int wtot;
    __shared__ int carry_sh;
    int tid = threadIdx.x;
    int lane = tid & 63;
    int w = tid >> 6;
    if (tid == 0) carry_sh = 0;
    __syncthreads();
    for (int base = 0; base < n; base += 1024) {
        int i = base + tid;
        int v = (i < n) ? cur[i] : 0;
        int s = v;
        #pragma unroll
        for (int d = 1; d < 64; d <<= 1) {
            int t = __shfl_up(s, d, 64);
            if (lane >= d) s += t;
        }
        if (lane == 63) wsum[w] = s;
        __syncthreads();
        if (w == 0 && lane < 16) {
            int t = wsum[lane];
            int ss = t;
            #pragma unroll
            for (int d = 1; d < 16; d <<= 1) {
                int u = __shfl_up(ss, d, 64);
                if (lane >= d) ss += u;
            }
            wsum[lane] = ss - t;
            if (lane == 15) wtot = ss;
        }
        __syncthreads();
        int carry = carry_sh;
        int excl = s - v + wsum[w] + carry;
        if (i < n) { off[i] = excl; cur[i] = excl; }
        __syncthreads();
        if (tid == 0) carry_sh += wtot;
        __syncthreads();
    }
    if (threadIdx.x == 0) off[n] = carry_sh;
}

// ---------------- conversions ----------------

__global__ void cvt_f32_bf16(const float* __restrict__ in, unsigned short* __restrict__ out, int n4) {
    int i = blockIdx.x * blockDim.x + threadIdx.x;
    if (i < n4) {
        float4 v = *(const float4*)&in[i * 4];
        ushort4 o;
        o.x = f2b(v.x); o.y = f2b(v.y); o.z = f2b(v.z); o.w = f2b(v.w);
        *(ushort4*)&out[i * 4] = o;
    }
}

// Pack W [K][256] fp32 -> Wp [K/32][256][32] bf16 with XOR-granule swizzle baked in.
struct PackArgs {
    const float* W[12];
    unsigned short* O[12];
    int K[12];
};

__global__ void pack_weights(PackArgs pa) {
    int m = blockIdx.y;
    int K = pa.K[m];
    int granules = (K / 32) * 1024;
    int p = blockIdx.x * blockDim.x + threadIdx.x;
    if (p >= granules) return;
    int kb = p >> 10;
    int r  = p & 1023;
    int c  = r >> 2;
    int gp = r & 3;
    int g  = gp ^ ((c >> 1) & 3);
    const float* W = pa.W[m];
    unsigned short* O = pa.O[m] + (size_t)p * 8;
    int krow = kb * 32 + g * 8;
    ushort4 lo, hi;
    lo.x = f2b(W[(size_t)(krow + 0) * HID + c]);
    lo.y = f2b(W[(size_t)(krow + 1) * HID + c]);
    lo.z = f2b(W[(size_t)(krow + 2) * HID + c]);
    lo.w = f2b(W[(size_t)(krow + 3) * HID + c]);
    hi.x = f2b(W[(size_t)(krow + 4) * HID + c]);
    hi.y = f2b(W[(size_t)(krow + 5) * HID + c]);
    hi.z = f2b(W[(size_t)(krow + 6) * HID + c]);
    hi.w = f2b(W[(size_t)(krow + 7) * HID + c]);
    *(ushort4*)&O[0] = lo;
    *(ushort4*)&O[4] = hi;
}

// ---------------- aggregation v2 ----------------
// One wave per node. Lane split: h = lane>>5 (edge parity), c = lane&31 (16B or 8B column slice).
// 8 edges in flight per iteration (4 pairs x 2 halves), cross-half shfl_xor reduce at end.

template <int F, bool MEAN>
__global__ __launch_bounds__(256) void agg_bf16(const unsigned short* __restrict__ xb,
                                                const int* __restrict__ off,
                                                const int* __restrict__ srt,
                                                unsigned short* __restrict__ msg) {
    constexpr int EL = F / 32;        // elems per lane: 8 (F=256) or 4 (F=128)
    int wv = threadIdx.x >> 6;
    int lane = threadIdx.x & 63;
    int h = lane >> 5, c = lane & 31;
    int node = blockIdx.x * 4 + wv;
    int s0 = off[node], s1 = off[node + 1];
    float acc[EL];
    #pragma unroll
    for (int i = 0; i < EL; ++i) acc[i] = 0.f;
    const unsigned short* colbase = xb + c * EL;

    auto addrow = [&](unsigned int v, int j) {
        acc[2 * j]     += b2f(v & 0xffffu);
        acc[2 * j + 1] += b2f(v >> 16);
    };

    int e = s0;
    for (; e + 7 < s1; e += 8) {
        int i0 = srt[e + 0 + h];
        int i1 = srt[e + 2 + h];
        int i2 = srt[e + 4 + h];
        int i3 = srt[e + 6 + h];
        if constexpr (EL == 8) {
            uint4 v0 = *(const uint4*)(colbase + (size_t)i0 * F);
            uint4 v1 = *(const uint4*)(colbase + (size_t)i1 * F);
            uint4 v2 = *(const uint4*)(colbase + (size_t)i2 * F);
            uint4 v3 = *(const uint4*)(colbase + (size_t)i3 * F);
            addrow(v0.x, 0); addrow(v0.y, 1); addrow(v0.z, 2); addrow(v0.w, 3);
            addrow(v1.x, 0); addrow(v1.y, 1); addrow(v1.z, 2); addrow(v1.w, 3);
            addrow(v2.x, 0); addrow(v2.y, 1); addrow(v2.z, 2); addrow(v2.w, 3);
            addrow(v3.x, 0); addrow(v3.y, 1); addrow(v3.z, 2); addrow(v3.w, 3);
        } else {
            uint2 v0 = *(const uint2*)(colbase + (size_t)i0 * F);
            uint2 v1 = *(const uint2*)(colbase + (size_t)i1 * F);
            uint2 v2 = *(const uint2*)(colbase + (size_t)i2 * F);
            uint2 v3 = *(const uint2*)(colbase + (size_t)i3 * F);
            addrow(v0.x, 0); addrow(v0.y, 1);
            addrow(v1.x, 0); addrow(v1.y, 1);
            addrow(v2.x, 0); addrow(v2.y, 1);
            addrow(v3.x, 0); addrow(v3.y, 1);
        }
    }
    for (; e + 1 < s1; e += 2) {
        int i0 = srt[e + h];
        if constexpr (EL == 8) {
            uint4 v0 = *(const uint4*)(colbase + (size_t)i0 * F);
            addrow(v0.x, 0); addrow(v0.y, 1); addrow(v0.z, 2); addrow(v0.w, 3);
        } else {
            uint2 v0 = *(const uint2*)(colbase + (size_t)i0 * F);
            addrow(v0.x, 0); addrow(v0.y, 1);
        }
    }
    if (e < s1 && h == 0) {
        int i0 = srt[e];
        if constexpr (EL == 8) {
            uint4 v0 = *(const uint4*)(colbase + (size_t)i0 * F);
            addrow(v0.x, 0); addrow(v0.y, 1); addrow(v0.z, 2); addrow(v0.w, 3);
        } else {
            uint2 v0 = *(const uint2*)(colbase + (size_t)i0 * F);
            addrow(v0.x, 0); addrow(v0.y, 1);
        }
    }

    // cross-half reduction
    #pragma unroll
    for (int i = 0; i < EL; ++i) acc[i] += __shfl_xor(acc[i], 32);

    if (h == 0) {
        if (MEAN) {
            float inv = 1.f / fmaxf((float)(s1 - s0), 1.f);
            #pragma unroll
            for (int i = 0; i < EL; ++i) acc[i] *= inv;
        }
        unsigned short* op = msg + (size_t)node * F + c * EL;
        if constexpr (EL == 8) {
            uint4 o;
            o.x = (unsigned int)f2b(acc[0]) | ((unsigned int)f2b(acc[1]) << 16);
            o.y = (unsigned int)f2b(acc[2]) | ((unsigned int)f2b(acc[3]) << 16);
            o.z = (unsigned int)f2b(acc[4]) | ((unsigned int)f2b(acc[5]) << 16);
            o.w = (unsigned int)f2b(acc[6]) | ((unsigned int)f2b(acc[7]) << 16);
            *(uint4*)op = o;
        } else {
            uint2 o;
            o.x = (unsigned int)f2b(acc[0]) | ((unsigned int)f2b(acc[1]) << 16);
            o.y = (unsigned int)f2b(acc[2]) | ((unsigned int)f2b(acc[3]) << 16);
            *(uint2*)op = o;
        }
    }
}

// ---------------- MFMA GEMM ----------------

#define GLOAD_LDS16(g, l) __builtin_amdgcn_global_load_lds( \
    (const __attribute__((address_space(1))) unsigned int*)(g), \
    (__attribute__((address_space(3))) unsigned int*)(l), 16, 0, 0)

template <int K, bool DUAL, bool RELU, bool OUT32>
__global__ __launch_bounds__(256) void gemm_mfma(const unsigned short* __restrict__ A1,
                                                 const unsigned short* __restrict__ Wp1,
                                                 const unsigned short* __restrict__ A2,
                                                 const unsigned short* __restrict__ Wp2,
                                                 const float* __restrict__ bias,
                                                 unsigned short* __restrict__ outb,
                                                 float* __restrict__ outf, int M) {
    constexpr int KB = K / 32;
    constexpr int NT = DUAL ? 2 * KB : KB;
    __shared__ unsigned short As[2][64 * 32];
    __shared__ unsigned short Bs[2][128 * 32];
    const int tid = threadIdx.x;
    const int lane = tid & 63;
    const int w = tid >> 6;
    const int wr = w >> 1, wc = w & 1;
    const int row0 = blockIdx.x * 64;
    const int colblk = blockIdx.y;

    f32x4 acc[2][4] = {};

    auto stage = [&](int buf, int t) {
        int pass = DUAL ? (t / KB) : 0;
        int kb = DUAL ? (t % KB) : t;
        const unsigned short* A = pass ? A2 : A1;
        const unsigned short* Wp = pass ? Wp2 : Wp1;
        {
            int row_l = tid >> 2, gp = tid & 3;
            int gs = gp ^ ((row_l >> 1) & 3);
            int row_g = row0 + row_l;
            if (row_g > M - 1) row_g = M - 1;
            const unsigned short* src = A + (size_t)row_g * K + kb * 32 + gs * 8;
            GLOAD_LDS16(src, &As[buf][w * 512]);
        }
        {
            const unsigned short* base = Wp + (size_t)kb * 8192 + (size_t)colblk * 4096;
            GLOAD_LDS16(base + tid * 8,        &Bs[buf][w * 512]);
            GLOAD_LDS16(base + 2048 + tid * 8, &Bs[buf][2048 + w * 512]);
        }
    };

    auto compute = [&](int buf) {
        short8v a[2], b[4];
        const int g = lane >> 4;
        #pragma unroll
        for (int rf = 0; rf < 2; ++rf) {
            int row_l = wr * 32 + rf * 16 + (lane & 15);
            int q = g ^ ((row_l >> 1) & 3);
            a[rf] = *(const short8v*)&As[buf][row_l * 32 + q * 8];
        }
        #pragma unroll
        for (int cf = 0; cf < 4; ++cf) {
            int col_l = wc * 64 + cf * 16 + (lane & 15);
            int q = g ^ ((col_l >> 1) & 3);
            b[cf] = *(const short8v*)&Bs[buf][col_l * 32 + q * 8];
        }
        #pragma unroll
        for (int cf = 0; cf < 4; ++cf)
            #pragma unroll
            for (int rf = 0; rf < 2; ++rf)
                acc[rf][cf] = __builtin_amdgcn_mfma_f32_16x16x32_bf16(a[rf], b[cf], acc[rf][cf], 0, 0, 0);
    };

    stage(0, 0);
    __syncthreads();
    int buf = 0;
    for (int t = 0; t < NT; ++t) {
        if (t + 1 < NT) stage(buf ^ 1, t + 1);
        compute(buf);
        __syncthreads();
        buf ^= 1;
    }

    #pragma unroll
    for (int cf = 0; cf < 4; ++cf) {
        int c = colblk * 128 + wc * 64 + cf * 16 + (lane & 15);
        float bv = bias[c];
        #pragma unroll
        for (int rf = 0; rf < 2; ++rf) {
            #pragma unroll
            for (int i = 0; i < 4; ++i) {
                int r = row0 + wr * 32 + rf * 16 + (lane >> 4) * 4 + i;
                if (r < M) {
                    float v = acc[rf][cf][i] + bv;
                    if (RELU) v = fmaxf(v, 0.f);
                    if (OUT32) outf[(size_t)r * HID + c] = v;
                    else       outb[(size_t)r * HID + c] = f2b(v);
                }
            }
        }
    }
}

// ---------------- launch ----------------

static inline char* align256(char* p) {
    return (char*)(((uintptr_t)p + 255) & ~(uintptr_t)255);
}

extern "C" void kernel_launch(void* const* d_in, const int* in_sizes, int n_in,
                              void* d_out, int out_size, void* d_ws, size_t ws_size,
                              hipStream_t stream) {
    const float* x0     = (const float*)d_in[0];
    const int*   ei_con = (const int*)d_in[1];
    const int*   ei_dst = (const int*)d_in[2];
    const int*   ei_trn = (const int*)d_in[3];
    const float* Wmat[12] = {
        (const float*)d_in[5],  (const float*)d_in[4],
        (const float*)d_in[8],  (const float*)d_in[7],
        (const float*)d_in[11], (const float*)d_in[10],
        (const float*)d_in[14], (const float*)d_in[13],
        (const float*)d_in[17], (const float*)d_in[16],
        (const float*)d_in[19],
        (const float*)d_in[19] + HID * HID
    };
    const float* b1 = (const float*)d_in[6];
    const float* b2 = (const float*)d_in[9];
    const float* b3 = (const float*)d_in[12];
    const float* b4 = (const float*)d_in[15];
    const float* b5 = (const float*)d_in[18];
    const float* bL = (const float*)d_in[20];

    const int eCon = in_sizes[1] / 2;
    const int eDst = in_sizes[2] / 2;
    const int eTrn = in_sizes[3] / 2;

    char* p = (char*)d_ws;
    int* cur_all = (int*)p; p = align256(p + 3 * N_NODES * 4);
    int* off_con = (int*)p; p = align256(p + (N_NODES + 1) * 4);
    int* off_dst = (int*)p; p = align256(p + (N_NODES + 1) * 4);
    int* off_trn = (int*)p; p = align256(p + (N_NODES + 1) * 4);
    int* srt_con = (int*)p; p = align256(p + E_CON * 4);
    int* srt_dst = (int*)p; p = align256(p + E_DST * 4);
    int* srt_trn = (int*)p; p = align256(p + E_TRN * 4);
    unsigned short* x0b  = (unsigned short*)p; p = align256(p + (size_t)N_NODES * IN_F * 2);
    unsigned short* msgb = (unsigned short*)p; p = align256(p + (size_t)N_NODES * HID * 2);
    unsigned short* xab  = (unsigned short*)p; p = align256(p + (size_t)N_NODES * HID * 2);
    unsigned short* xbb  = (unsigned short*)p; p = align256(p + (size_t)N_NODES * HID * 2);
    unsigned short* WpBuf[12];
    PackArgs pa;
    for (int m = 0; m < 12; ++m) {
        int K = (m < 2) ? IN_F : HID;
        WpBuf[m] = (unsigned short*)p; p = align256(p + (size_t)K * HID * 2);
        pa.W[m] = Wmat[m];
        pa.O[m] = WpBuf[m];
        pa.K[m] = K;
    }
    float* outp = (float*)d_out;

    CsrArgs ca;
    ca.g[0] = { ei_con, ei_con + eCon, eCon, cur_all,              off_con, srt_con };
    ca.g[1] = { ei_dst, ei_dst + eDst, eDst, cur_all + N_NODES,    off_dst, srt_dst };
    ca.g[2] = { ei_trn, ei_trn + eTrn, eTrn, cur_all + 2*N_NODES,  off_trn, srt_trn };

    // ---- prep: weight pack + x0 conversion + cursor zero ----
    pack_weights<<<dim3(32, 12), 256, 0, stream>>>(pa);
    cvt_f32_bf16<<<(N_NODES * IN_F / 4 + 255) / 256, 256, 0, stream>>>(x0, x0b, N_NODES * IN_F / 4);
    zero_cur<<<(3 * N_NODES + 255) / 256, 256, 0, stream>>>(cur_all);

    // ---- CSR build ----
    dim3 hgrid((eCon + 255) / 256, 3);
    hist3<<<hgrid, 256, 0, stream>>>(ca);
    scan3<<<3, 1024, 0, stream>>>(ca);
    fill3<<<hgrid, 256, 0, stream>>>(ca);

    dim3 ggrid((N_NODES + 63) / 64, 2);
    const int agrid = N_NODES / 4;

    // conv1: relu(msg@Wrel1 + x0@Wroot1 + b1), connections, K=128
    agg_bf16<IN_F, false><<<agrid, 256, 0, stream>>>(x0b, off_con, srt_con, msgb);
    gemm_mfma<IN_F, true, true, false><<<ggrid, 256, 0, stream>>>(msgb, WpBuf[0], x0b, WpBuf[1], b1, xab, nullptr, N_NODES);

    // conv2: (no relu), trains
    agg_bf16<HID, false><<<agrid, 256, 0, stream>>>(xab, off_trn, srt_trn, msgb);
    gemm_mfma<HID, true, false, false><<<ggrid, 256, 0, stream>>>(msgb, WpBuf[2], xab, WpBuf[3], b2, xbb, nullptr, N_NODES);

    // conv3 x2: relu, mean, connections
    agg_bf16<HID, true><<<agrid, 256, 0, stream>>>(xbb, off_con, srt_con, msgb);
    gemm_mfma<HID, true, true, false><<<ggrid, 256, 0, stream>>>(msgb, WpBuf[4], xbb, WpBuf[5], b3, xab, nullptr, N_NODES);
    agg_bf16<HID, true><<<agrid, 256, 0, stream>>>(xab, off_con, srt_con, msgb);
    gemm_mfma<HID, true, true, false><<<ggrid, 256, 0, stream>>>(msgb, WpBuf[4], xab, WpBuf[5], b3, xbb, nullptr, N_NODES);

    // conv4: relu, add, destinations
    agg_bf16<HID, false><<<agrid, 256, 0, stream>>>(xbb, off_dst, srt_dst, msgb);
    gemm_mfma<HID, true, true, false><<<ggrid, 256, 0, stream>>>(msgb, WpBuf[6], xbb, WpBuf[7], b4, xab, nullptr, N_NODES);

    // conv5 x2: relu, add, connections
    agg_bf16<HID, false><<<agrid, 256, 0, stream>>>(xab, off_con, srt_con, msgb);
    gemm_mfma<HID, true, true, false><<<ggrid, 256, 0, stream>>>(msgb, WpBuf[8], xab, WpBuf[9], b5, xbb, nullptr, N_NODES);
    agg_bf16<HID, false><<<agrid, 256, 0, stream>>>(xbb, off_con, srt_con, msgb);
    gemm_mfma<HID, true, true, false><<<ggrid, 256, 0, stream>>>(msgb, WpBuf[8], xbb, WpBuf[9], b5, xab, nullptr, N_NODES);

    // final linears
    gemm_mfma<HID, false, false, false><<<ggrid, 256, 0, stream>>>(xab, WpBuf[10], nullptr, nullptr, bL, xbb, nullptr, N_NODES);
    gemm_mfma<HID, false, false, true><<<ggrid, 256, 0, stream>>>(xbb, WpBuf[11], nullptr, nullptr, bL + HID, nullptr, outp, N_NODES);
}

// Round 5
// 304.549 us; speedup vs baseline: 2.7395x; 1.0182x over previous
//
#include <hip/hip_runtime.h>
#include <hip/hip_bf16.h>

#define N_NODES 10000
#define HID 256
#define IN_F 128
#define E_CON 320000
#define E_DST 100000
#define E_TRN 50000

typedef __attribute__((ext_vector_type(8))) short short8v;
typedef __attribute__((ext_vector_type(4))) float f32x4;

__device__ __forceinline__ float b2f(unsigned int u) {
    return __uint_as_float(u << 16);
}
__device__ __forceinline__ unsigned short f2b(float f) {
    unsigned int u = __float_as_uint(f);
    unsigned int r = (u + 0x7fffu + ((u >> 16) & 1u)) >> 16;
    return (unsigned short)r;
}

// ---------------- CSR build (fused, 3 graphs) ----------------

struct GraphDesc {
    const int* src;
    const int* dst;
    int nE;
    int* cur;
    int* off;
    int* srt;
};
struct CsrArgs { GraphDesc g[3]; };

__global__ void zero_cur(int* __restrict__ cur) {
    int i = blockIdx.x * blockDim.x + threadIdx.x;
    if (i < 3 * N_NODES) cur[i] = 0;
}

__global__ void hist3(CsrArgs a) {
    const GraphDesc& gg = a.g[blockIdx.y];
    int i = blockIdx.x * blockDim.x + threadIdx.x;
    if (i < gg.nE) atomicAdd(&gg.cur[gg.dst[i]], 1);
}

__global__ void fill3(CsrArgs a) {
    const GraphDesc& gg = a.g[blockIdx.y];
    int i = blockIdx.x * blockDim.x + threadIdx.x;
    if (i < gg.nE) {
        int p = atomicAdd(&gg.cur[gg.dst[i]], 1);
        gg.srt[p] = gg.src[i];
    }
}

// One block per graph, 1024 threads, shfl-based exclusive scan over N_NODES.
__global__ __launch_bounds__(1024) void scan3(CsrArgs a) {
    const GraphDesc& gg = a.g[blockIdx.x];
    int* cur = gg.cur;
    int* off = gg.off;
    const int n = N_NODES;
    __shared__ int wsum[16];
    __shared__ int wtot;
    __shared__ int carry_sh;
    int tid = threadIdx.x;
    int lane = tid & 63;
    int w = tid >> 6;
    if (tid == 0) carry_sh = 0;
    __syncthreads();
    for (int base = 0; base < n; base += 1024) {
        int i = base + tid;
        int v = (i < n) ? cur[i] : 0;
        int s = v;
        #pragma unroll
        for (int d = 1; d < 64; d <<= 1) {
            int t = __shfl_up(s, d, 64);
            if (lane >= d) s += t;
        }
        if (lane == 63) wsum[w] = s;
        __syncthreads();
        if (w == 0 && lane < 16) {
            int t = wsum[lane];
            int ss = t;
            #pragma unroll
            for (int d = 1; d < 16; d <<= 1) {
                int u = __shfl_up(ss, d, 64);
                if (lane >= d) ss += u;
            }
            wsum[lane] = ss - t;
            if (lane == 15) wtot = ss;
        }
        __syncthreads();
        int carry = carry_sh;
        int excl = s - v + wsum[w] + carry;
        if (i < n) { off[i] = excl; cur[i] = excl; }
        __syncthreads();
        if (tid == 0) carry_sh += wtot;
        __syncthreads();
    }
    if (threadIdx.x == 0) off[n] = carry_sh;
}

// ---------------- conversions ----------------

__global__ void cvt_f32_bf16(const float* __restrict__ in, unsigned short* __restrict__ out, int n4) {
    int i = blockIdx.x * blockDim.x + threadIdx.x;
    if (i < n4) {
        float4 v = *(const float4*)&in[i * 4];
        ushort4 o;
        o.x = f2b(v.x); o.y = f2b(v.y); o.z = f2b(v.z); o.w = f2b(v.w);
        *(ushort4*)&out[i * 4] = o;
    }
}

// Pack W [K][256] fp32 -> Wp [K/32][256][32] bf16 with XOR-granule swizzle baked in.
struct PackArgs {
    const float* W[12];
    unsigned short* O[12];
    int K[12];
};

__global__ void pack_weights(PackArgs pa) {
    int m = blockIdx.y;
    int K = pa.K[m];
    int granules = (K / 32) * 1024;
    int p = blockIdx.x * blockDim.x + threadIdx.x;
    if (p >= granules) return;
    int kb = p >> 10;
    int r  = p & 1023;
    int c  = r >> 2;
    int gp = r & 3;
    int g  = gp ^ ((c >> 1) & 3);
    const float* W = pa.W[m];
    unsigned short* O = pa.O[m] + (size_t)p * 8;
    int krow = kb * 32 + g * 8;
    ushort4 lo, hi;
    lo.x = f2b(W[(size_t)(krow + 0) * HID + c]);
    lo.y = f2b(W[(size_t)(krow + 1) * HID + c]);
    lo.z = f2b(W[(size_t)(krow + 2) * HID + c]);
    lo.w = f2b(W[(size_t)(krow + 3) * HID + c]);
    hi.x = f2b(W[(size_t)(krow + 4) * HID + c]);
    hi.y = f2b(W[(size_t)(krow + 5) * HID + c]);
    hi.z = f2b(W[(size_t)(krow + 6) * HID + c]);
    hi.w = f2b(W[(size_t)(krow + 7) * HID + c]);
    *(ushort4*)&O[0] = lo;
    *(ushort4*)&O[4] = hi;
}

// ---------------- aggregation v3: column-blocked for per-XCD L2 residency ----------------
// Block = 4 nodes (1 wave each) x 128 columns. grid = (N/4, F/128).
// Working set per column-half = N_NODES*128*2B = 2.56 MB < 4 MB per-XCD L2.
// Wave split: h = lane>>5 picks edge parity, c = lane&31 picks 4-col slice (uint2 loads).
// 16 edges in flight per wave iteration for latency hiding.

template <int F, bool MEAN>
__global__ __launch_bounds__(256) void agg_bf16(const unsigned short* __restrict__ xb,
                                                const int* __restrict__ off,
                                                const int* __restrict__ srt,
                                                unsigned short* __restrict__ msg) {
    int wv = threadIdx.x >> 6;
    int lane = threadIdx.x & 63;
    int h = lane >> 5, c = lane & 31;
    int node = blockIdx.x * 4 + wv;
    int col0 = blockIdx.y * 128 + c * 4;
    int s0 = off[node], s1 = off[node + 1];
    float a0 = 0.f, a1 = 0.f, a2 = 0.f, a3 = 0.f;
    const unsigned short* colbase = xb + col0;

    auto addrow = [&](uint2 v) {
        a0 += b2f(v.x & 0xffffu); a1 += b2f(v.x >> 16);
        a2 += b2f(v.y & 0xffffu); a3 += b2f(v.y >> 16);
    };

    int e = s0;
    for (; e + 15 < s1; e += 16) {
        int i0 = srt[e + 0 + h];
        int i1 = srt[e + 2 + h];
        int i2 = srt[e + 4 + h];
        int i3 = srt[e + 6 + h];
        int i4 = srt[e + 8 + h];
        int i5 = srt[e + 10 + h];
        int i6 = srt[e + 12 + h];
        int i7 = srt[e + 14 + h];
        uint2 v0 = *(const uint2*)(colbase + (size_t)i0 * F);
        uint2 v1 = *(const uint2*)(colbase + (size_t)i1 * F);
        uint2 v2 = *(const uint2*)(colbase + (size_t)i2 * F);
        uint2 v3 = *(const uint2*)(colbase + (size_t)i3 * F);
        uint2 v4 = *(const uint2*)(colbase + (size_t)i4 * F);
        uint2 v5 = *(const uint2*)(colbase + (size_t)i5 * F);
        uint2 v6 = *(const uint2*)(colbase + (size_t)i6 * F);
        uint2 v7 = *(const uint2*)(colbase + (size_t)i7 * F);
        addrow(v0); addrow(v1); addrow(v2); addrow(v3);
        addrow(v4); addrow(v5); addrow(v6); addrow(v7);
    }
    for (; e + 1 < s1; e += 2) {
        int i0 = srt[e + h];
        addrow(*(const uint2*)(colbase + (size_t)i0 * F));
    }
    if (e < s1 && h == 0) {
        int i0 = srt[e];
        addrow(*(const uint2*)(colbase + (size_t)i0 * F));
    }

    a0 += __shfl_xor(a0, 32);
    a1 += __shfl_xor(a1, 32);
    a2 += __shfl_xor(a2, 32);
    a3 += __shfl_xor(a3, 32);

    if (h == 0) {
        if (MEAN) {
            float inv = 1.f / fmaxf((float)(s1 - s0), 1.f);
            a0 *= inv; a1 *= inv; a2 *= inv; a3 *= inv;
        }
        uint2 o;
        o.x = (unsigned int)f2b(a0) | ((unsigned int)f2b(a1) << 16);
        o.y = (unsigned int)f2b(a2) | ((unsigned int)f2b(a3) << 16);
        *(uint2*)(msg + (size_t)node * F + col0) = o;
    }
}

// ---------------- MFMA GEMM v2: 32x128 block tile, 4 waves (16x64 each) ----------------
// grid = (ceil(M/32), 2). ~626 blocks -> ~2.4 blocks/CU.

#define GLOAD_LDS16(g, l) __builtin_amdgcn_global_load_lds( \
    (const __attribute__((address_space(1))) unsigned int*)(g), \
    (__attribute__((address_space(3))) unsigned int*)(l), 16, 0, 0)

template <int K, bool DUAL, bool RELU, bool OUT32>
__global__ __launch_bounds__(256) void gemm_mfma(const unsigned short* __restrict__ A1,
                                                 const unsigned short* __restrict__ Wp1,
                                                 const unsigned short* __restrict__ A2,
                                                 const unsigned short* __restrict__ Wp2,
                                                 const float* __restrict__ bias,
                                                 unsigned short* __restrict__ outb,
                                                 float* __restrict__ outf, int M) {
    constexpr int KB = K / 32;
    constexpr int NT = DUAL ? 2 * KB : KB;
    __shared__ unsigned short As[2][32 * 32];    // 2 KB per buf
    __shared__ unsigned short Bs[2][128 * 32];   // 8 KB per buf
    const int tid = threadIdx.x;
    const int lane = tid & 63;
    const int w = tid >> 6;
    const int wr = w >> 1, wc = w & 1;           // wave tile: rows wr*16, cols wc*64
    const int row0 = blockIdx.x * 32;
    const int colblk = blockIdx.y;

    f32x4 acc[4] = {};

    auto stage = [&](int buf, int t) {
        int pass = DUAL ? (t / KB) : 0;
        int kb = DUAL ? (t % KB) : t;
        const unsigned short* A = pass ? A2 : A1;
        const unsigned short* Wp = pass ? Wp2 : Wp1;
        // A tile: 32 rows x 32 k (2 KB) -> threads 0..127 (waves 0,1)
        if (w < 2) {
            int row_l = tid >> 2, gp = tid & 3;
            int gs = gp ^ ((row_l >> 1) & 3);
            int row_g = row0 + row_l;
            if (row_g > M - 1) row_g = M - 1;
            const unsigned short* src = A + (size_t)row_g * K + kb * 32 + gs * 8;
            GLOAD_LDS16(src, &As[buf][w * 512]);
        }
        // B tile: 128 cols x 32 k (8 KB), two calls, all 4 waves
        {
            const unsigned short* base = Wp + (size_t)kb * 8192 + (size_t)colblk * 4096;
            GLOAD_LDS16(base + tid * 8,        &Bs[buf][w * 512]);
            GLOAD_LDS16(base + 2048 + tid * 8, &Bs[buf][2048 + w * 512]);
        }
    };

    auto compute = [&](int buf) {
        short8v a, b[4];
        const int g = lane >> 4;
        {
            int row_l = wr * 16 + (lane & 15);
            int q = g ^ ((row_l >> 1) & 3);
            a = *(const short8v*)&As[buf][row_l * 32 + q * 8];
        }
        #pragma unroll
        for (int cf = 0; cf < 4; ++cf) {
            int col_l = wc * 64 + cf * 16 + (lane & 15);
            int q = g ^ ((col_l >> 1) & 3);
            b[cf] = *(const short8v*)&Bs[buf][col_l * 32 + q * 8];
        }
        #pragma unroll
        for (int cf = 0; cf < 4; ++cf)
            acc[cf] = __builtin_amdgcn_mfma_f32_16x16x32_bf16(a, b[cf], acc[cf], 0, 0, 0);
    };

    stage(0, 0);
    __syncthreads();
    int buf = 0;
    for (int t = 0; t < NT; ++t) {
        if (t + 1 < NT) stage(buf ^ 1, t + 1);
        compute(buf);
        __syncthreads();
        buf ^= 1;
    }

    #pragma unroll
    for (int cf = 0; cf < 4; ++cf) {
        int c = colblk * 128 + wc * 64 + cf * 16 + (lane & 15);
        float bv = bias[c];
        #pragma unroll
        for (int i = 0; i < 4; ++i) {
            int r = row0 + wr * 16 + (lane >> 4) * 4 + i;
            if (r < M) {
                float v = acc[cf][i] + bv;
                if (RELU) v = fmaxf(v, 0.f);
                if (OUT32) outf[(size_t)r * HID + c] = v;
                else       outb[(size_t)r * HID + c] = f2b(v);
            }
        }
    }
}

// ---------------- launch ----------------

static inline char* align256(char* p) {
    return (char*)(((uintptr_t)p + 255) & ~(uintptr_t)255);
}

extern "C" void kernel_launch(void* const* d_in, const int* in_sizes, int n_in,
                              void* d_out, int out_size, void* d_ws, size_t ws_size,
                              hipStream_t stream) {
    const float* x0     = (const float*)d_in[0];
    const int*   ei_con = (const int*)d_in[1];
    const int*   ei_dst = (const int*)d_in[2];
    const int*   ei_trn = (const int*)d_in[3];
    const float* Wmat[12] = {
        (const float*)d_in[5],  (const float*)d_in[4],
        (const float*)d_in[8],  (const float*)d_in[7],
        (const float*)d_in[11], (const float*)d_in[10],
        (const float*)d_in[14], (const float*)d_in[13],
        (const float*)d_in[17], (const float*)d_in[16],
        (const float*)d_in[19],
        (const float*)d_in[19] + HID * HID
    };
    const float* b1 = (const float*)d_in[6];
    const float* b2 = (const float*)d_in[9];
    const float* b3 = (const float*)d_in[12];
    const float* b4 = (const float*)d_in[15];
    const float* b5 = (const float*)d_in[18];
    const float* bL = (const float*)d_in[20];

    const int eCon = in_sizes[1] / 2;
    const int eDst = in_sizes[2] / 2;
    const int eTrn = in_sizes[3] / 2;

    char* p = (char*)d_ws;
    int* cur_all = (int*)p; p = align256(p + 3 * N_NODES * 4);
    int* off_con = (int*)p; p = align256(p + (N_NODES + 1) * 4);
    int* off_dst = (int*)p; p = align256(p + (N_NODES + 1) * 4);
    int* off_trn = (int*)p; p = align256(p + (N_NODES + 1) * 4);
    int* srt_con = (int*)p; p = align256(p + E_CON * 4);
    int* srt_dst = (int*)p; p = align256(p + E_DST * 4);
    int* srt_trn = (int*)p; p = align256(p + E_TRN * 4);
    unsigned short* x0b  = (unsigned short*)p; p = align256(p + (size_t)N_NODES * IN_F * 2);
    unsigned short* msgb = (unsigned short*)p; p = align256(p + (size_t)N_NODES * HID * 2);
    unsigned short* xab  = (unsigned short*)p; p = align256(p + (size_t)N_NODES * HID * 2);
    unsigned short* xbb  = (unsigned short*)p; p = align256(p + (size_t)N_NODES * HID * 2);
    unsigned short* WpBuf[12];
    PackArgs pa;
    for (int m = 0; m < 12; ++m) {
        int K = (m < 2) ? IN_F : HID;
        WpBuf[m] = (unsigned short*)p; p = align256(p + (size_t)K * HID * 2);
        pa.W[m] = Wmat[m];
        pa.O[m] = WpBuf[m];
        pa.K[m] = K;
    }
    float* outp = (float*)d_out;

    CsrArgs ca;
    ca.g[0] = { ei_con, ei_con + eCon, eCon, cur_all,              off_con, srt_con };
    ca.g[1] = { ei_dst, ei_dst + eDst, eDst, cur_all + N_NODES,    off_dst, srt_dst };
    ca.g[2] = { ei_trn, ei_trn + eTrn, eTrn, cur_all + 2*N_NODES,  off_trn, srt_trn };

    // ---- prep ----
    pack_weights<<<dim3(32, 12), 256, 0, stream>>>(pa);
    cvt_f32_bf16<<<(N_NODES * IN_F / 4 + 255) / 256, 256, 0, stream>>>(x0, x0b, N_NODES * IN_F / 4);
    zero_cur<<<(3 * N_NODES + 255) / 256, 256, 0, stream>>>(cur_all);

    // ---- CSR build ----
    dim3 hgrid((eCon + 255) / 256, 3);
    hist3<<<hgrid, 256, 0, stream>>>(ca);
    scan3<<<3, 1024, 0, stream>>>(ca);
    fill3<<<hgrid, 256, 0, stream>>>(ca);

    dim3 ggrid((N_NODES + 31) / 32, 2);
    dim3 agrid1(N_NODES / 4, 1);     // F=128: one column block
    dim3 agrid2(N_NODES / 4, 2);     // F=256: two column halves

    // conv1: relu(msg@Wrel1 + x0@Wroot1 + b1), connections, K=128
    agg_bf16<IN_F, false><<<agrid1, 256, 0, stream>>>(x0b, off_con, srt_con, msgb);
    gemm_mfma<IN_F, true, true, false><<<ggrid, 256, 0, stream>>>(msgb, WpBuf[0], x0b, WpBuf[1], b1, xab, nullptr, N_NODES);

    // conv2: (no relu), trains
    agg_bf16<HID, false><<<agrid2, 256, 0, stream>>>(xab, off_trn, srt_trn, msgb);
    gemm_mfma<HID, true, false, false><<<ggrid, 256, 0, stream>>>(msgb, WpBuf[2], xab, WpBuf[3], b2, xbb, nullptr, N_NODES);

    // conv3 x2: relu, mean, connections
    agg_bf16<HID, true><<<agrid2, 256, 0, stream>>>(xbb, off_con, srt_con, msgb);
    gemm_mfma<HID, true, true, false><<<ggrid, 256, 0, stream>>>(msgb, WpBuf[4], xbb, WpBuf[5], b3, xab, nullptr, N_NODES);
    agg_bf16<HID, true><<<agrid2, 256, 0, stream>>>(xab, off_con, srt_con, msgb);
    gemm_mfma<HID, true, true, false><<<ggrid, 256, 0, stream>>>(msgb, WpBuf[4], xab, WpBuf[5], b3, xbb, nullptr, N_NODES);

    // conv4: relu, add, destinations
    agg_bf16<HID, false><<<agrid2, 256, 0, stream>>>(xbb, off_dst, srt_dst, msgb);
    gemm_mfma<HID, true, true, false><<<ggrid, 256, 0, stream>>>(msgb, WpBuf[6], xbb, WpBuf[7], b4, xab, nullptr, N_NODES);

    // conv5 x2: relu, add, connections
    agg_bf16<HID, false><<<agrid2, 256, 0, stream>>>(xab, off_con, srt_con, msgb);
    gemm_mfma<HID, true, true, false><<<ggrid, 256, 0, stream>>>(msgb, WpBuf[8], xab, WpBuf[9], b5, xbb, nullptr, N_NODES);
    agg_bf16<HID, false><<<agrid2, 256, 0, stream>>>(xbb, off_con, srt_con, msgb);
    gemm_mfma<HID, true, true, false><<<ggrid, 256, 0, stream>>>(msgb, WpBuf[8], xbb, WpBuf[9], b5, xab, nullptr, N_NODES);

    // final linears
    gemm_mfma<HID, false, false, false><<<ggrid, 256, 0, stream>>>(xab, WpBuf[10], nullptr, nullptr, bL, xbb, nullptr, N_NODES);
    gemm_mfma<HID, false, false, true><<<ggrid, 256, 0, stream>>>(xbb, WpBuf[11], nullptr, nullptr, bL + HID, nullptr, outp, N_NODES);
}

// Round 6
// 272.849 us; speedup vs baseline: 3.0577x; 1.1162x over previous
//
#include <hip/hip_runtime.h>
#include <hip/hip_bf16.h>

#define N_NODES 10000
#define HID 256
#define IN_F 128
#define E_CON 320000
#define E_DST 100000
#define E_TRN 50000

typedef __attribute__((ext_vector_type(8))) short short8v;
typedef __attribute__((ext_vector_type(4))) float f32x4;
typedef unsigned int uint4v __attribute__((ext_vector_type(4)));

__device__ __forceinline__ float b2f(unsigned int u) {
    return __uint_as_float(u << 16);
}
__device__ __forceinline__ unsigned short f2b(float f) {
    unsigned int u = __float_as_uint(f);
    unsigned int r = (u + 0x7fffu + ((u >> 16) & 1u)) >> 16;
    return (unsigned short)r;
}

// ---------------- CSR build (fused, 3 graphs) ----------------

struct GraphDesc {
    const int* src;
    const int* dst;
    int nE;
    int* cur;
    int* off;
    int* srt;
};
struct CsrArgs { GraphDesc g[3]; };

__global__ void hist3(CsrArgs a) {
    const GraphDesc& gg = a.g[blockIdx.y];
    int i = blockIdx.x * blockDim.x + threadIdx.x;
    if (i < gg.nE) atomicAdd(&gg.cur[gg.dst[i]], 1);
}

__global__ void fill3(CsrArgs a) {
    const GraphDesc& gg = a.g[blockIdx.y];
    int i = blockIdx.x * blockDim.x + threadIdx.x;
    if (i < gg.nE) {
        int p = atomicAdd(&gg.cur[gg.dst[i]], 1);
        gg.srt[p] = gg.src[i];
    }
}

// One block per graph, 1024 threads, shfl-based exclusive scan over N_NODES.
__global__ __launch_bounds__(1024) void scan3(CsrArgs a) {
    const GraphDesc& gg = a.g[blockIdx.x];
    int* cur = gg.cur;
    int* off = gg.off;
    const int n = N_NODES;
    __shared__ int wsum[16];
    __shared__ int wtot;
    __shared__ int carry_sh;
    int tid = threadIdx.x;
    int lane = tid & 63;
    int w = tid >> 6;
    if (tid == 0) carry_sh = 0;
    __syncthreads();
    for (int base = 0; base < n; base += 1024) {
        int i = base + tid;
        int v = (i < n) ? cur[i] : 0;
        int s = v;
        #pragma unroll
        for (int d = 1; d < 64; d <<= 1) {
            int t = __shfl_up(s, d, 64);
            if (lane >= d) s += t;
        }
        if (lane == 63) wsum[w] = s;
        __syncthreads();
        if (w == 0 && lane < 16) {
            int t = wsum[lane];
            int ss = t;
            #pragma unroll
            for (int d = 1; d < 16; d <<= 1) {
                int u = __shfl_up(ss, d, 64);
                if (lane >= d) ss += u;
            }
            wsum[lane] = ss - t;
            if (lane == 15) wtot = ss;
        }
        __syncthreads();
        int carry = carry_sh;
        int excl = s - v + wsum[w] + carry;
        if (i < n) { off[i] = excl; cur[i] = excl; }
        __syncthreads();
        if (tid == 0) carry_sh += wtot;
        __syncthreads();
    }
    if (threadIdx.x == 0) off[n] = carry_sh;
}

// ---------------- fused prep: weight pack + x0 cvt + cursor zero ----------------

struct PackArgs {
    const float* W[12];
    unsigned short* O[12];
    int K[12];
};

#define PREP_PACK_BLKS 384      /* 12 matrices x 32 blocks */
#define PREP_CVT_BLKS  1250     /* 320000 float4 / 256 */
#define PREP_ZERO_BLKS 118      /* 30000 ints / 256 */

__global__ void prep_kernel(PackArgs pa, const float* __restrict__ x0,
                            unsigned short* __restrict__ x0b, int* __restrict__ cur_all) {
    int bid = blockIdx.x;
    int tid = threadIdx.x;
    if (bid < PREP_PACK_BLKS) {
        int m = bid >> 5;
        int K = pa.K[m];
        int granules = (K / 32) * 1024;
        int p = (bid & 31) * 256 + tid;
        if (p >= granules) return;
        int kb = p >> 10;
        int r  = p & 1023;
        int c  = r >> 2;
        int gp = r & 3;
        int g  = gp ^ ((c >> 1) & 3);
        const float* W = pa.W[m];
        unsigned short* O = pa.O[m] + (size_t)p * 8;
        int krow = kb * 32 + g * 8;
        ushort4 lo, hi;
        lo.x = f2b(W[(size_t)(krow + 0) * HID + c]);
        lo.y = f2b(W[(size_t)(krow + 1) * HID + c]);
        lo.z = f2b(W[(size_t)(krow + 2) * HID + c]);
        lo.w = f2b(W[(size_t)(krow + 3) * HID + c]);
        hi.x = f2b(W[(size_t)(krow + 4) * HID + c]);
        hi.y = f2b(W[(size_t)(krow + 5) * HID + c]);
        hi.z = f2b(W[(size_t)(krow + 6) * HID + c]);
        hi.w = f2b(W[(size_t)(krow + 7) * HID + c]);
        *(ushort4*)&O[0] = lo;
        *(ushort4*)&O[4] = hi;
    } else if (bid < PREP_PACK_BLKS + PREP_CVT_BLKS) {
        int i = (bid - PREP_PACK_BLKS) * 256 + tid;   // < 320000
        float4 v = *(const float4*)&x0[(size_t)i * 4];
        ushort4 o;
        o.x = f2b(v.x); o.y = f2b(v.y); o.z = f2b(v.z); o.w = f2b(v.w);
        *(ushort4*)&x0b[(size_t)i * 4] = o;
    } else {
        int i = (bid - PREP_PACK_BLKS - PREP_CVT_BLKS) * 256 + tid;
        if (i < 3 * N_NODES) cur_all[i] = 0;
    }
}

// ---------------- aggregation v4: XCD-pinned column halves ----------------
// blockIdx.x % 8 selects the XCD (HW round-robin); half = bid & 1 ties each
// 128-column half to a fixed XCD parity -> per-XCD L2 working set:
// x-half 2.56 MB + srt 1.28 MB < 4 MB (intra-kernel resident).
// Wave: 4-way edge split, h = lane>>4 (edge), c = lane&15 (8-col slice, uint4 load).
// 16 edges in flight per iteration. msg written via nontemporal store (no L2 pollution).

template <int F, bool MEAN>
__global__ __launch_bounds__(256) void agg_bf16(const unsigned short* __restrict__ xb,
                                                const int* __restrict__ off,
                                                const int* __restrict__ srt,
                                                unsigned short* __restrict__ msg) {
    constexpr int HALVES = F / 128;
    int bid = blockIdx.x;
    int half = (HALVES == 2) ? (bid & 1) : 0;
    int nodeblk = (HALVES == 2) ? (bid >> 1) : bid;
    int wv = threadIdx.x >> 6;
    int lane = threadIdx.x & 63;
    int h = lane >> 4, c = lane & 15;
    int node = nodeblk * 4 + wv;
    int col0 = half * 128 + c * 8;
    int s0 = off[node], s1 = off[node + 1];
    float acc[8];
    #pragma unroll
    for (int j = 0; j < 8; ++j) acc[j] = 0.f;
    const unsigned short* colbase = xb + col0;

    auto addrow = [&](uint4v v) {
        acc[0] += b2f(v.x & 0xffffu); acc[1] += b2f(v.x >> 16);
        acc[2] += b2f(v.y & 0xffffu); acc[3] += b2f(v.y >> 16);
        acc[4] += b2f(v.z & 0xffffu); acc[5] += b2f(v.z >> 16);
        acc[6] += b2f(v.w & 0xffffu); acc[7] += b2f(v.w >> 16);
    };

    int e = s0;
    for (; e + 15 < s1; e += 16) {
        int i0 = srt[e + h];
        int i1 = srt[e + 4 + h];
        int i2 = srt[e + 8 + h];
        int i3 = srt[e + 12 + h];
        uint4v v0 = *(const uint4v*)(colbase + (size_t)i0 * F);
        uint4v v1 = *(const uint4v*)(colbase + (size_t)i1 * F);
        uint4v v2 = *(const uint4v*)(colbase + (size_t)i2 * F);
        uint4v v3 = *(const uint4v*)(colbase + (size_t)i3 * F);
        addrow(v0); addrow(v1); addrow(v2); addrow(v3);
    }
    for (; e + 3 < s1; e += 4) {
        int i0 = srt[e + h];
        addrow(*(const uint4v*)(colbase + (size_t)i0 * F));
    }
    int rem = s1 - e;
    if (h < rem) {
        int i0 = srt[e + h];
        addrow(*(const uint4v*)(colbase + (size_t)i0 * F));
    }

    #pragma unroll
    for (int j = 0; j < 8; ++j) {
        acc[j] += __shfl_xor(acc[j], 16);
        acc[j] += __shfl_xor(acc[j], 32);
    }

    if (h == 0) {
        if (MEAN) {
            float inv = 1.f / fmaxf((float)(s1 - s0), 1.f);
            #pragma unroll
            for (int j = 0; j < 8; ++j) acc[j] *= inv;
        }
        uint4v o;
        o.x = (unsigned int)f2b(acc[0]) | ((unsigned int)f2b(acc[1]) << 16);
        o.y = (unsigned int)f2b(acc[2]) | ((unsigned int)f2b(acc[3]) << 16);
        o.z = (unsigned int)f2b(acc[4]) | ((unsigned int)f2b(acc[5]) << 16);
        o.w = (unsigned int)f2b(acc[6]) | ((unsigned int)f2b(acc[7]) << 16);
        __builtin_nontemporal_store(o, (uint4v*)(msg + (size_t)node * F + col0));
    }
}

// ---------------- MFMA GEMM: 32x128 block tile, 4 waves (16x64 each) ----------------

#define GLOAD_LDS16(g, l) __builtin_amdgcn_global_load_lds( \
    (const __attribute__((address_space(1))) unsigned int*)(g), \
    (__attribute__((address_space(3))) unsigned int*)(l), 16, 0, 0)

template <int K, bool DUAL, bool RELU, bool OUT32>
__global__ __launch_bounds__(256) void gemm_mfma(const unsigned short* __restrict__ A1,
                                                 const unsigned short* __restrict__ Wp1,
                                                 const unsigned short* __restrict__ A2,
                                                 const unsigned short* __restrict__ Wp2,
                                                 const float* __restrict__ bias,
                                                 unsigned short* __restrict__ outb,
                                                 float* __restrict__ outf, int M) {
    constexpr int KB = K / 32;
    constexpr int NT = DUAL ? 2 * KB : KB;
    __shared__ unsigned short As[2][32 * 32];
    __shared__ unsigned short Bs[2][128 * 32];
    const int tid = threadIdx.x;
    const int lane = tid & 63;
    const int w = tid >> 6;
    const int wr = w >> 1, wc = w & 1;
    const int row0 = blockIdx.x * 32;
    const int colblk = blockIdx.y;

    f32x4 acc[4] = {};

    auto stage = [&](int buf, int t) {
        int pass = DUAL ? (t / KB) : 0;
        int kb = DUAL ? (t % KB) : t;
        const unsigned short* A = pass ? A2 : A1;
        const unsigned short* Wp = pass ? Wp2 : Wp1;
        if (w < 2) {
            int row_l = tid >> 2, gp = tid & 3;
            int gs = gp ^ ((row_l >> 1) & 3);
            int row_g = row0 + row_l;
            if (row_g > M - 1) row_g = M - 1;
            const unsigned short* src = A + (size_t)row_g * K + kb * 32 + gs * 8;
            GLOAD_LDS16(src, &As[buf][w * 512]);
        }
        {
            const unsigned short* base = Wp + (size_t)kb * 8192 + (size_t)colblk * 4096;
            GLOAD_LDS16(base + tid * 8,        &Bs[buf][w * 512]);
            GLOAD_LDS16(base + 2048 + tid * 8, &Bs[buf][2048 + w * 512]);
        }
    };

    auto compute = [&](int buf) {
        short8v a, b[4];
        const int g = lane >> 4;
        {
            int row_l = wr * 16 + (lane & 15);
            int q = g ^ ((row_l >> 1) & 3);
            a = *(const short8v*)&As[buf][row_l * 32 + q * 8];
        }
        #pragma unroll
        for (int cf = 0; cf < 4; ++cf) {
            int col_l = wc * 64 + cf * 16 + (lane & 15);
            int q = g ^ ((col_l >> 1) & 3);
            b[cf] = *(const short8v*)&Bs[buf][col_l * 32 + q * 8];
        }
        #pragma unroll
        for (int cf = 0; cf < 4; ++cf)
            acc[cf] = __builtin_amdgcn_mfma_f32_16x16x32_bf16(a, b[cf], acc[cf], 0, 0, 0);
    };

    stage(0, 0);
    __syncthreads();
    int buf = 0;
    for (int t = 0; t < NT; ++t) {
        if (t + 1 < NT) stage(buf ^ 1, t + 1);
        compute(buf);
        __syncthreads();
        buf ^= 1;
    }

    #pragma unroll
    for (int cf = 0; cf < 4; ++cf) {
        int c = colblk * 128 + wc * 64 + cf * 16 + (lane & 15);
        float bv = bias[c];
        #pragma unroll
        for (int i = 0; i < 4; ++i) {
            int r = row0 + wr * 16 + (lane >> 4) * 4 + i;
            if (r < M) {
                float v = acc[cf][i] + bv;
                if (RELU) v = fmaxf(v, 0.f);
                if (OUT32) outf[(size_t)r * HID + c] = v;
                else       outb[(size_t)r * HID + c] = f2b(v);
            }
        }
    }
}

// ---------------- launch ----------------

static inline char* align256(char* p) {
    return (char*)(((uintptr_t)p + 255) & ~(uintptr_t)255);
}

extern "C" void kernel_launch(void* const* d_in, const int* in_sizes, int n_in,
                              void* d_out, int out_size, void* d_ws, size_t ws_size,
                              hipStream_t stream) {
    const float* x0     = (const float*)d_in[0];
    const int*   ei_con = (const int*)d_in[1];
    const int*   ei_dst = (const int*)d_in[2];
    const int*   ei_trn = (const int*)d_in[3];
    const float* Wmat[12] = {
        (const float*)d_in[5],  (const float*)d_in[4],
        (const float*)d_in[8],  (const float*)d_in[7],
        (const float*)d_in[11], (const float*)d_in[10],
        (const float*)d_in[14], (const float*)d_in[13],
        (const float*)d_in[17], (const float*)d_in[16],
        (const float*)d_in[19],
        (const float*)d_in[19] + HID * HID
    };
    const float* b1 = (const float*)d_in[6];
    const float* b2 = (const float*)d_in[9];
    const float* b3 = (const float*)d_in[12];
    const float* b4 = (const float*)d_in[15];
    const float* b5 = (const float*)d_in[18];
    const float* bL = (const float*)d_in[20];

    const int eCon = in_sizes[1] / 2;
    const int eDst = in_sizes[2] / 2;
    const int eTrn = in_sizes[3] / 2;

    char* p = (char*)d_ws;
    int* cur_all = (int*)p; p = align256(p + 3 * N_NODES * 4);
    int* off_con = (int*)p; p = align256(p + (N_NODES + 1) * 4);
    int* off_dst = (int*)p; p = align256(p + (N_NODES + 1) * 4);
    int* off_trn = (int*)p; p = align256(p + (N_NODES + 1) * 4);
    int* srt_con = (int*)p; p = align256(p + E_CON * 4);
    int* srt_dst = (int*)p; p = align256(p + E_DST * 4);
    int* srt_trn = (int*)p; p = align256(p + E_TRN * 4);
    unsigned short* x0b  = (unsigned short*)p; p = align256(p + (size_t)N_NODES * IN_F * 2);
    unsigned short* msgb = (unsigned short*)p; p = align256(p + (size_t)N_NODES * HID * 2);
    unsigned short* xab  = (unsigned short*)p; p = align256(p + (size_t)N_NODES * HID * 2);
    unsigned short* xbb  = (unsigned short*)p; p = align256(p + (size_t)N_NODES * HID * 2);
    unsigned short* WpBuf[12];
    PackArgs pa;
    for (int m = 0; m < 12; ++m) {
        int K = (m < 2) ? IN_F : HID;
        WpBuf[m] = (unsigned short*)p; p = align256(p + (size_t)K * HID * 2);
        pa.W[m] = Wmat[m];
        pa.O[m] = WpBuf[m];
        pa.K[m] = K;
    }
    float* outp = (float*)d_out;

    CsrArgs ca;
    ca.g[0] = { ei_con, ei_con + eCon, eCon, cur_all,              off_con, srt_con };
    ca.g[1] = { ei_dst, ei_dst + eDst, eDst, cur_all + N_NODES,    off_dst, srt_dst };
    ca.g[2] = { ei_trn, ei_trn + eTrn, eTrn, cur_all + 2*N_NODES,  off_trn, srt_trn };

    // ---- fused prep: pack + cvt + zero ----
    prep_kernel<<<PREP_PACK_BLKS + PREP_CVT_BLKS + PREP_ZERO_BLKS, 256, 0, stream>>>(pa, x0, x0b, cur_all);

    // ---- CSR build ----
    dim3 hgrid((eCon + 255) / 256, 3);
    hist3<<<hgrid, 256, 0, stream>>>(ca);
    scan3<<<3, 1024, 0, stream>>>(ca);
    fill3<<<hgrid, 256, 0, stream>>>(ca);

    dim3 ggrid((N_NODES + 31) / 32, 2);
    const int agrid1 = N_NODES / 4;        // F=128: one column half
    const int agrid2 = (N_NODES / 4) * 2;  // F=256: XCD-pinned halves interleaved

    // conv1: relu(msg@Wrel1 + x0@Wroot1 + b1), connections, K=128
    agg_bf16<IN_F, false><<<agrid1, 256, 0, stream>>>(x0b, off_con, srt_con, msgb);
    gemm_mfma<IN_F, true, true, false><<<ggrid, 256, 0, stream>>>(msgb, WpBuf[0], x0b, WpBuf[1], b1, xab, nullptr, N_NODES);

    // conv2: (no relu), trains
    agg_bf16<HID, false><<<agrid2, 256, 0, stream>>>(xab, off_trn, srt_trn, msgb);
    gemm_mfma<HID, true, false, false><<<ggrid, 256, 0, stream>>>(msgb, WpBuf[2], xab, WpBuf[3], b2, xbb, nullptr, N_NODES);

    // conv3 x2: relu, mean, connections
    agg_bf16<HID, true><<<agrid2, 256, 0, stream>>>(xbb, off_con, srt_con, msgb);
    gemm_mfma<HID, true, true, false><<<ggrid, 256, 0, stream>>>(msgb, WpBuf[4], xbb, WpBuf[5], b3, xab, nullptr, N_NODES);
    agg_bf16<HID, true><<<agrid2, 256, 0, stream>>>(xab, off_con, srt_con, msgb);
    gemm_mfma<HID, true, true, false><<<ggrid, 256, 0, stream>>>(msgb, WpBuf[4], xab, WpBuf[5], b3, xbb, nullptr, N_NODES);

    // conv4: relu, add, destinations
    agg_bf16<HID, false><<<agrid2, 256, 0, stream>>>(xbb, off_dst, srt_dst, msgb);
    gemm_mfma<HID, true, true, false><<<ggrid, 256, 0, stream>>>(msgb, WpBuf[6], xbb, WpBuf[7], b4, xab, nullptr, N_NODES);

    // conv5 x2: relu, add, connections
    agg_bf16<HID, false><<<agrid2, 256, 0, stream>>>(xab, off_con, srt_con, msgb);
    gemm_mfma<HID, true, true, false><<<ggrid, 256, 0, stream>>>(msgb, WpBuf[8], xab, WpBuf[9], b5, xbb, nullptr, N_NODES);
    agg_bf16<HID, false><<<agrid2, 256, 0, stream>>>(xbb, off_con, srt_con, msgb);
    gemm_mfma<HID, true, true, false><<<ggrid, 256, 0, stream>>>(msgb, WpBuf[8], xbb, WpBuf[9], b5, xab, nullptr, N_NODES);

    // final linears
    gemm_mfma<HID, false, false, false><<<ggrid, 256, 0, stream>>>(xab, WpBuf[10], nullptr, nullptr, bL, xbb, nullptr, N_NODES);
    gemm_mfma<HID, false, false, true><<<ggrid, 256, 0, stream>>>(xbb, WpBuf[11], nullptr, nullptr, bL + HID, nullptr, outp, N_NODES);
}